// Round 10
// baseline (3690.772 us; speedup 1.0000x reference)
//
#include <hip/hip_runtime.h>

#define NN 100000
#define EE 3200000
#define EPSF 1e-5f

typedef unsigned short u16;
typedef short bf16x8 __attribute__((ext_vector_type(8)));
typedef float f32x4 __attribute__((ext_vector_type(4)));

static inline int cdiv(int a, int b) { return (a + b - 1) / b; }

__device__ __forceinline__ float b2f(u16 u) {
    return __uint_as_float((unsigned int)u << 16);
}
__device__ __forceinline__ u16 f2b(float f) {
    unsigned int i = __float_as_uint(f);
    return (u16)((i + 0x7FFFu + ((i >> 16) & 1u)) >> 16);  // RNE
}
// packed edge: [31:17] = positive float top bits, [16:0] = src index
__device__ __forceinline__ int ep_src(unsigned int p) { return (int)(p & 0x1FFFFu); }
__device__ __forceinline__ float ep_w(unsigned int p) {
    return __uint_as_float(p & 0xFFFE0000u);
}

// ---------------- zero-init (graph-capture-safe) ----------------
__global__ void k_init(int* __restrict__ deg, int* __restrict__ cursor,
                       float* __restrict__ stats) {
    int i = blockIdx.x * 256 + threadIdx.x;
    if (i < NN) {
        deg[i] = 0;
        cursor[i] = 0;
    }
    if (i < 2048) stats[i] = 0.f;
}

// ---------------- degree histogram ----------------
__global__ void k_deg(const int* __restrict__ col, int* __restrict__ deg) {
    int i = blockIdx.x * 256 + threadIdx.x;
    if (i < EE) atomicAdd(&deg[col[i]], 1);
}

__global__ void k_dinv(const int* __restrict__ deg, float* __restrict__ dinv) {
    int i = blockIdx.x * 256 + threadIdx.x;
    if (i < NN) {
        int d = deg[i];
        dinv[i] = d > 0 ? rsqrtf((float)d) : 0.f;
    }
}

// ------- exclusive scan: 1024 threads, 98 contiguous elems per thread -------
__global__ void k_scan(const int* __restrict__ deg, int* __restrict__ offs) {
    __shared__ int sh[1024];
    int tid = threadIdx.x;
    int start = tid * 98;
    int end = min(start + 98, NN);
    int sum = 0;
    for (int i = start; i < end; ++i) sum += deg[i];
    sh[tid] = sum;
    __syncthreads();
    for (int off = 1; off < 1024; off <<= 1) {
        int t = (tid >= off) ? sh[tid - off] : 0;
        __syncthreads();
        sh[tid] += t;
        __syncthreads();
    }
    int base = tid ? sh[tid - 1] : 0;
    for (int i = start; i < end; ++i) {
        offs[i] = base;
        base += deg[i];
    }
    if (tid == 1023) offs[NN] = sh[1023];
}

// ---------------- CSR scatter: pack (w:15 | src:17) into one u32 ----------------
__global__ void k_scatter(const int* __restrict__ row, const int* __restrict__ col,
                          const float* __restrict__ dinv, const int* __restrict__ offs,
                          int* __restrict__ cursor, unsigned int* __restrict__ ep) {
    int i = blockIdx.x * 256 + threadIdx.x;
    if (i < EE) {
        int c = col[i], r = row[i];
        int pos = offs[c] + atomicAdd(&cursor[c], 1);
        float w = dinv[r] * dinv[c];  // >= 0
        unsigned int u = __float_as_uint(w);
        unsigned int rb = (u + 0xFFFFu + ((u >> 17) & 1u)) & 0xFFFE0000u;  // RNE @ 7-bit man
        ep[pos] = rb | (unsigned int)r;
    }
}

// ---------------- convert fp32 array -> bf16 (n4 = count of float4s) ----------------
__global__ void k_cvt(const float* __restrict__ src, u16* __restrict__ dst, int n4) {
    int idx = blockIdx.x * 256 + threadIdx.x;
    if (idx >= n4) return;
    float4 v = ((const float4*)src)[idx];
    ushort4 o;
    o.x = f2b(v.x);
    o.y = f2b(v.y);
    o.z = f2b(v.z);
    o.w = f2b(v.w);
    ((ushort4*)dst)[idx] = o;
}

// ---------------- convert fp32 array -> fp8 e4m3 (n4 = count of float4s) ----------------
__global__ void k_cvt8f(const float* __restrict__ src, unsigned char* __restrict__ dst,
                        int n4) {
    int idx = blockIdx.x * 256 + threadIdx.x;
    if (idx >= n4) return;
    float4 v = ((const float4*)src)[idx];
    int p0 = __builtin_amdgcn_cvt_pk_fp8_f32(v.x, v.y, 0, false);
    int p1 = __builtin_amdgcn_cvt_pk_fp8_f32(v.z, v.w, 0, false);
    uchar4 o;
    o.x = (unsigned char)(p0 & 0xFF);
    o.y = (unsigned char)((p0 >> 8) & 0xFF);
    o.z = (unsigned char)(p1 & 0xFF);
    o.w = (unsigned char)((p1 >> 8) & 0xFF);
    ((uchar4*)dst)[idx] = o;
}

// ---- convert a width-128 bf16 slice (ld elems) -> fp8 (ld bytes), sequential ----
__global__ void k_cvt8s(const u16* __restrict__ src, int lds_, unsigned char* __restrict__ dst,
                        int ldd) {
    int idx = blockIdx.x * 256 + threadIdx.x;  // over NN*64 (2 elems each)
    if (idx >= NN * 64) return;
    int node = idx >> 6, f2 = (idx & 63) << 1;
    ushort2 v = *(const ushort2*)(src + (size_t)node * lds_ + f2);
    int pk = __builtin_amdgcn_cvt_pk_fp8_f32(b2f(v.x), b2f(v.y), 0, false);
    uchar2 o;
    o.x = (unsigned char)(pk & 0xFF);
    o.y = (unsigned char)((pk >> 8) & 0xFF);
    *(uchar2*)(dst + (size_t)node * ldd + f2) = o;
}

// ---- gather propagation, width 128, 64 thr/node, 4x unroll.
// S8: source fp8 (ldin in bytes) else bf16 (ldin in elems).
// OB: write bf16 out; O8: write fp8 out. ----
template <int S8, int OB, int O8>
__global__ void k_prop_t(const void* __restrict__ in, int ldin, u16* __restrict__ outb,
                         int ldob, unsigned char* __restrict__ out8, int ldo8,
                         const int* __restrict__ offs, const unsigned int* __restrict__ ep) {
    int node = blockIdx.x;
    int f2 = threadIdx.x << 1;
    int s = offs[node], e = offs[node + 1];
    const u16* inb = (const u16*)in;
    const unsigned char* in8 = (const unsigned char*)in;
    float a0 = 0.f, a1 = 0.f;
    int t = s;
    for (; t + 4 <= e; t += 4) {
        unsigned int p0 = ep[t], p1 = ep[t + 1], p2 = ep[t + 2], p3 = ep[t + 3];
        float x0, y0, x1, y1, x2, y2, x3, y3;
        if (S8) {
            uchar2 c0 = *(const uchar2*)(in8 + (size_t)ep_src(p0) * ldin + f2);
            uchar2 c1 = *(const uchar2*)(in8 + (size_t)ep_src(p1) * ldin + f2);
            uchar2 c2 = *(const uchar2*)(in8 + (size_t)ep_src(p2) * ldin + f2);
            uchar2 c3 = *(const uchar2*)(in8 + (size_t)ep_src(p3) * ldin + f2);
            int w0 = c0.x | (c0.y << 8), w1 = c1.x | (c1.y << 8);
            int w2 = c2.x | (c2.y << 8), w3 = c3.x | (c3.y << 8);
            x0 = __builtin_amdgcn_cvt_f32_fp8(w0, 0);
            y0 = __builtin_amdgcn_cvt_f32_fp8(w0, 1);
            x1 = __builtin_amdgcn_cvt_f32_fp8(w1, 0);
            y1 = __builtin_amdgcn_cvt_f32_fp8(w1, 1);
            x2 = __builtin_amdgcn_cvt_f32_fp8(w2, 0);
            y2 = __builtin_amdgcn_cvt_f32_fp8(w2, 1);
            x3 = __builtin_amdgcn_cvt_f32_fp8(w3, 0);
            y3 = __builtin_amdgcn_cvt_f32_fp8(w3, 1);
        } else {
            ushort2 v0 = *(const ushort2*)(inb + (size_t)ep_src(p0) * ldin + f2);
            ushort2 v1 = *(const ushort2*)(inb + (size_t)ep_src(p1) * ldin + f2);
            ushort2 v2 = *(const ushort2*)(inb + (size_t)ep_src(p2) * ldin + f2);
            ushort2 v3 = *(const ushort2*)(inb + (size_t)ep_src(p3) * ldin + f2);
            x0 = b2f(v0.x);
            y0 = b2f(v0.y);
            x1 = b2f(v1.x);
            y1 = b2f(v1.y);
            x2 = b2f(v2.x);
            y2 = b2f(v2.y);
            x3 = b2f(v3.x);
            y3 = b2f(v3.y);
        }
        float w0 = ep_w(p0), w1 = ep_w(p1), w2 = ep_w(p2), w3 = ep_w(p3);
        a0 = fmaf(w0, x0, a0);
        a1 = fmaf(w0, y0, a1);
        a0 = fmaf(w1, x1, a0);
        a1 = fmaf(w1, y1, a1);
        a0 = fmaf(w2, x2, a0);
        a1 = fmaf(w2, y2, a1);
        a0 = fmaf(w3, x3, a0);
        a1 = fmaf(w3, y3, a1);
    }
    for (; t < e; ++t) {
        unsigned int p0 = ep[t];
        float x0, y0;
        if (S8) {
            uchar2 c0 = *(const uchar2*)(in8 + (size_t)ep_src(p0) * ldin + f2);
            int w = c0.x | (c0.y << 8);
            x0 = __builtin_amdgcn_cvt_f32_fp8(w, 0);
            y0 = __builtin_amdgcn_cvt_f32_fp8(w, 1);
        } else {
            ushort2 v0 = *(const ushort2*)(inb + (size_t)ep_src(p0) * ldin + f2);
            x0 = b2f(v0.x);
            y0 = b2f(v0.y);
        }
        float w0 = ep_w(p0);
        a0 = fmaf(w0, x0, a0);
        a1 = fmaf(w0, y0, a1);
    }
    if (OB) {
        ushort2 o;
        o.x = f2b(a0);
        o.y = f2b(a1);
        *(ushort2*)(outb + (size_t)node * ldob + f2) = o;
    }
    if (O8) {
        int pk = __builtin_amdgcn_cvt_pk_fp8_f32(a0, a1, 0, false);
        uchar2 o8;
        o8.x = (unsigned char)(pk & 0xFF);
        o8.y = (unsigned char)((pk >> 8) & 0xFF);
        *(uchar2*)(out8 + (size_t)node * ldo8 + f2) = o8;
    }
}

// ---- width-16 fp32 propagation with addend (Horner), 16 nodes/block, 8x unroll ----
__global__ void k_prop16(const float* __restrict__ in, int ldin,
                         const float* __restrict__ add, int ldadd,
                         float* __restrict__ out, const float* __restrict__ bias,
                         const int* __restrict__ offs, const unsigned int* __restrict__ ep) {
    int node = blockIdx.x * 16 + (threadIdx.x >> 4);
    if (node >= NN) return;
    int f = threadIdx.x & 15;
    float acc = add[(size_t)node * ldadd + f];
    int s = offs[node], e = offs[node + 1];
    int t = s;
    for (; t + 8 <= e; t += 8) {
        unsigned int p[8];
        float v[8];
#pragma unroll
        for (int u = 0; u < 8; ++u) p[u] = ep[t + u];
#pragma unroll
        for (int u = 0; u < 8; ++u) v[u] = in[(size_t)ep_src(p[u]) * ldin + f];
#pragma unroll
        for (int u = 0; u < 8; ++u) acc = fmaf(ep_w(p[u]), v[u], acc);
    }
    for (; t < e; ++t) {
        unsigned int p0 = ep[t];
        acc = fmaf(ep_w(p0), in[(size_t)ep_src(p0) * ldin + f], acc);
    }
    if (bias) acc += bias[f];
    out[node * 16 + f] = acc;
}

// ---- MFMA bf16 GEMM, 128x128 tile, up to 4 A/B sources (K quarters of Kq).
// A sources bf16 (lda in elems) or fp8 e4m3 (lda in bytes) per a8mask bit.
// B bf16 TRANSPOSED: B[n][k], stride ldb; Nn = true output width (row-clamped).
// cmode: 0 = write fp32, 1 = write bf16 fresh, 2 = accumulate into bf16 C ----
#define LDS_LD 40
__global__ __launch_bounds__(256) void k_gemm_mfma(
    const void* __restrict__ A0, int lda0, const void* __restrict__ A1, int lda1,
    const void* __restrict__ A2, int lda2, const void* __restrict__ A3, int lda3, int a8mask,
    const u16* __restrict__ B0, const u16* __restrict__ B1, const u16* __restrict__ B2,
    const u16* __restrict__ B3, int ldb, void* __restrict__ Cv, int ldc, int M, int Nn,
    int Ktot, int Kq, const float* __restrict__ bias, int relu, int cmode) {
    __shared__ u16 As[128 * LDS_LD];
    __shared__ u16 Bs[128 * LDS_LD];
    int tid = threadIdx.x;
    int wave = tid >> 6, lane = tid & 63;
    int quad = lane >> 4, lq = lane & 15;
    int m0 = blockIdx.y * 128, n0 = blockIdx.x * 128;
    f32x4 acc[2][8] = {};

    for (int ks = 0; ks < Ktot; ks += 32) {
        int src = ks / Kq;
        int kk = ks - src * Kq;
        const void* Ap = src == 0 ? A0 : src == 1 ? A1 : src == 2 ? A2 : A3;
        int lda = src == 0 ? lda0 : src == 1 ? lda1 : src == 2 ? lda2 : lda3;
        const u16* Bp = src == 0 ? B0 : src == 1 ? B1 : src == 2 ? B2 : B3;
        if ((a8mask >> src) & 1) {
            const unsigned char* A8 = (const unsigned char*)Ap;
#pragma unroll
            for (int i = 0; i < 2; ++i) {
                int s = tid + i * 256;
                int r = s >> 2, ko = (s & 3) << 3;
                int gr = m0 + r;
                if (gr > M - 1) gr = M - 1;
                uint2 w = *(const uint2*)(A8 + (size_t)gr * lda + kk + ko);
                ushort h0 = f2b(__builtin_amdgcn_cvt_f32_fp8((int)w.x, 0));
                ushort h1 = f2b(__builtin_amdgcn_cvt_f32_fp8((int)w.x, 1));
                ushort h2 = f2b(__builtin_amdgcn_cvt_f32_fp8((int)w.x, 2));
                ushort h3 = f2b(__builtin_amdgcn_cvt_f32_fp8((int)w.x, 3));
                ushort h4 = f2b(__builtin_amdgcn_cvt_f32_fp8((int)w.y, 0));
                ushort h5 = f2b(__builtin_amdgcn_cvt_f32_fp8((int)w.y, 1));
                ushort h6 = f2b(__builtin_amdgcn_cvt_f32_fp8((int)w.y, 2));
                ushort h7 = f2b(__builtin_amdgcn_cvt_f32_fp8((int)w.y, 3));
                uint4 o;
                o.x = (unsigned)h0 | ((unsigned)h1 << 16);
                o.y = (unsigned)h2 | ((unsigned)h3 << 16);
                o.z = (unsigned)h4 | ((unsigned)h5 << 16);
                o.w = (unsigned)h6 | ((unsigned)h7 << 16);
                *(uint4*)&As[r * LDS_LD + ko] = o;
            }
        } else {
            const u16* Ab = (const u16*)Ap;
#pragma unroll
            for (int i = 0; i < 2; ++i) {
                int s = tid + i * 256;
                int r = s >> 2, ko = (s & 3) << 3;
                int gr = m0 + r;
                if (gr > M - 1) gr = M - 1;
                uint4 v = *(const uint4*)(Ab + (size_t)gr * lda + kk + ko);
                *(uint4*)&As[r * LDS_LD + ko] = v;
            }
        }
        // stage B (transposed in global): 128 n-rows x 32 k, 2 x uint4 per thread
#pragma unroll
        for (int i = 0; i < 2; ++i) {
            int s = tid + i * 256;
            int n = s >> 2, ko = (s & 3) << 3;
            int gn = n0 + n;
            if (gn > Nn - 1) gn = Nn - 1;
            uint4 v = *(const uint4*)(Bp + (size_t)gn * ldb + kk + ko);
            *(uint4*)&Bs[n * LDS_LD + ko] = v;
        }
        __syncthreads();
        bf16x8 af[2], bfr[8];
#pragma unroll
        for (int i = 0; i < 2; ++i)
            af[i] = *(bf16x8*)&As[(wave * 32 + i * 16 + lq) * LDS_LD + quad * 8];
#pragma unroll
        for (int j = 0; j < 8; ++j)
            bfr[j] = *(bf16x8*)&Bs[(j * 16 + lq) * LDS_LD + quad * 8];
#pragma unroll
        for (int i = 0; i < 2; ++i)
#pragma unroll
            for (int j = 0; j < 8; ++j)
                acc[i][j] = __builtin_amdgcn_mfma_f32_16x16x32_bf16(af[i], bfr[j], acc[i][j],
                                                                    0, 0, 0);
        __syncthreads();
    }
#pragma unroll
    for (int i = 0; i < 2; ++i) {
#pragma unroll
        for (int j = 0; j < 8; ++j) {
            int c = n0 + j * 16 + lq;
            if (c >= Nn) continue;
            float bcol = bias ? bias[c] : 0.f;
            int rbase = m0 + wave * 32 + i * 16 + quad * 4;
#pragma unroll
            for (int reg = 0; reg < 4; ++reg) {
                int r = rbase + reg;
                if (r >= M) continue;
                float t = acc[i][j][reg];
                if (cmode == 2) t += b2f(*((u16*)Cv + (size_t)r * ldc + c));
                t += bcol;
                if (relu) t = fmaxf(t, 0.f);
                if (cmode == 0)
                    ((float*)Cv)[(size_t)r * ldc + c] = t;
                else
                    *((u16*)Cv + (size_t)r * ldc + c) = f2b(t);
            }
        }
    }
}

// ---------------- column stats (sum, sumsq) over bf16 NNx512 ----------------
__global__ void k_colstats(const u16* __restrict__ X, int ld, float* __restrict__ stats) {
    int r0 = blockIdx.x * 64;
    int c = threadIdx.x * 2;
    float s0 = 0, s1 = 0, q0 = 0, q1 = 0;
    int rend = min(r0 + 64, NN);
    for (int r = r0; r < rend; ++r) {
        ushort2 v = *(const ushort2*)(X + (size_t)r * ld + c);
        float x0 = b2f(v.x), x1 = b2f(v.y);
        s0 += x0;
        s1 += x1;
        q0 += x0 * x0;
        q1 += x1 * x1;
    }
    atomicAdd(&stats[c], s0);
    atomicAdd(&stats[c + 1], s1);
    atomicAdd(&stats[512 + c], q0);
    atomicAdd(&stats[512 + c + 1], q1);
}

// ---------------- graphnorm apply (in place, bf16) ----------------
__global__ void k_gnorm(u16* __restrict__ X, int ld, const float* __restrict__ stats,
                        const float* __restrict__ w, const float* __restrict__ b,
                        const float* __restrict__ a) {
    int i = blockIdx.x;
    int c = threadIdx.x * 2;
    const float invn = 1.f / NN;
    ushort2 v = *(ushort2*)(X + (size_t)i * ld + c);
    float x0 = b2f(v.x), x1 = b2f(v.y);
    {
        float m = stats[c] * invn, q = stats[512 + c] * invn, al = a[c];
        float var = q - (2.f * al - al * al) * m * m;
        x0 = (x0 - al * m) * rsqrtf(var + EPSF) * w[c] + b[c];
    }
    {
        int c1 = c + 1;
        float m = stats[c1] * invn, q = stats[512 + c1] * invn, al = a[c1];
        float var = q - (2.f * al - al * al) * m * m;
        x1 = (x1 - al * m) * rsqrtf(var + EPSF) * w[c1] + b[c1];
    }
    v.x = f2b(x0);
    v.y = f2b(x1);
    *(ushort2*)(X + (size_t)i * ld + c) = v;
}

// ---- transpose weights: src (KH, I, O) fp32 -> dst (KH, O, I) bf16 ----
__global__ void k_wt(const float* __restrict__ src, u16* __restrict__ dst, int I, int O,
                     int total) {
    int idx = blockIdx.x * 256 + threadIdx.x;
    if (idx >= total) return;
    int io = I * O;
    int k = idx / io, rem = idx - k * io;
    int n = rem / I, i = rem - n * I;
    dst[idx] = f2b(src[(size_t)k * io + (size_t)i * O + n]);
}

// ---- W3 (4,512,16) fp32 -> W3T (64, 512) bf16 : W3T[k*16+f][i] = W3[k][i][f] ----
__global__ void k_wt3(const float* __restrict__ W3, u16* __restrict__ W3T) {
    int idx = blockIdx.x * 256 + threadIdx.x;
    if (idx >= 64 * 512) return;
    int n = idx >> 9, i = idx & 511;
    int k = n >> 4, f = n & 15;
    W3T[idx] = f2b(W3[((size_t)k * 512 + i) * 16 + f]);
}

extern "C" void kernel_launch(void* const* d_in, const int* in_sizes, int n_in,
                              void* d_out, int out_size, void* d_ws, size_t ws_size,
                              hipStream_t stream) {
    const float* x = (const float*)d_in[0];
    const int* ei = (const int*)d_in[1];
    const float* W1 = (const float*)d_in[2];
    const float* b1 = (const float*)d_in[3];
    const float* W2 = (const float*)d_in[4];
    const float* b2 = (const float*)d_in[5];
    const float* W3 = (const float*)d_in[6];
    const float* b3 = (const float*)d_in[7];
    const float* g1w = (const float*)d_in[8];
    const float* g1b = (const float*)d_in[9];
    const float* g1a = (const float*)d_in[10];
    const float* g2w = (const float*)d_in[11];
    const float* g2b = (const float*)d_in[12];
    const float* g2a = (const float*)d_in[13];
    const int* row = ei;
    const int* col = ei + EE;

    char* p = (char*)d_ws;
    auto alloc = [&](size_t bytes) {
        char* r = p;
        p += (bytes + 255) & ~(size_t)255;
        return r;
    };
    // Total workspace ~247.5 MB (unchanged from rounds 8/9 proven budget)
    u16* H1 = (u16*)alloc((size_t)NN * 512 * 2);                  // 102.4 MB
    u16* Y = (u16*)alloc((size_t)NN * 512 * 2);                   // 102.4 MB
    unsigned char* XF = (unsigned char*)alloc((size_t)NN * 256);  // 25.6 MB: F8a|F8b
    unsigned int* ep = (unsigned int*)alloc((size_t)EE * 4);      // 12.8 MB
    u16* W1T = (u16*)alloc((size_t)4 * 512 * 128 * 2);            // 0.5 MB
    u16* W2T = (u16*)alloc((size_t)4 * 512 * 512 * 2);            // 2.0 MB
    u16* W3T = (u16*)alloc(64 * 512 * 2);                         // 64 KB
    float* dinv = (float*)alloc((size_t)NN * 4);
    float* stats = (float*)alloc(2048 * 4);
    int* deg = (int*)alloc((size_t)NN * 4);
    int* offs = (int*)alloc((size_t)(NN + 1) * 4);
    int* cursor = (int*)alloc((size_t)NN * 4);
    (void)ws_size;
    (void)in_sizes;
    (void)n_in;
    (void)out_size;

    unsigned char* F8a = XF;
    unsigned char* F8b = XF + (size_t)NN * 128;
    // L1 bf16 scratch parked in Y (free until first L2 GEMM):
    u16* xb = Y;                        // N x 128, ld 128
    u16* hop2b = Y + (size_t)NN * 128;  // N x 128, ld 128
    u16* hop3b = Y + (size_t)2 * NN * 128;

    // ---- CSR build + weight transpose/convert
    k_init<<<cdiv(NN, 256), 256, 0, stream>>>(deg, cursor, stats);
    k_deg<<<cdiv(EE, 256), 256, 0, stream>>>(col, deg);
    k_dinv<<<cdiv(NN, 256), 256, 0, stream>>>(deg, dinv);
    k_scan<<<1, 1024, 0, stream>>>(deg, offs);
    k_scatter<<<cdiv(EE, 256), 256, 0, stream>>>(row, col, dinv, offs, cursor, ep);
    k_wt<<<cdiv(4 * 128 * 512, 256), 256, 0, stream>>>(W1, W1T, 128, 512, 4 * 128 * 512);
    k_wt<<<cdiv(4 * 512 * 512, 256), 256, 0, stream>>>(W2, W2T, 512, 512, 4 * 512 * 512);
    k_wt3<<<cdiv(64 * 512, 256), 256, 0, stream>>>(W3, W3T);

    dim3 gg(512 / 128, cdiv(NN, 128));  // (4, 782), 128x128 tiles
    const size_t WQ = (size_t)512 * 512;   // per-hop stride in W2T
    const size_t W1Q = (size_t)512 * 128;  // per-hop stride in W1T

    // ---- layer 1: H1 = sum_k (A^k x) W1[k]
    k_cvt<<<cdiv(NN * 32, 256), 256, 0, stream>>>(x, xb, NN * 32);
    k_cvt8f<<<cdiv(NN * 32, 256), 256, 0, stream>>>(x, F8b, NN * 32);  // xf8
    k_prop_t<1, 0, 1><<<NN, 64, 0, stream>>>(F8b, 128, nullptr, 0, F8a, 128, offs, ep);
    k_gemm_mfma<<<gg, 256, 0, stream>>>(xb, 128, F8a, 128, xb, 128, xb, 128, 2, W1T,
                                        W1T + W1Q, W1T, W1T, 128, H1, 512, NN, 512, 256, 128,
                                        nullptr, 0, 1);
    k_prop_t<1, 1, 1><<<NN, 64, 0, stream>>>(F8a, 128, hop2b, 128, F8b, 128, offs, ep);
    k_prop_t<1, 1, 0><<<NN, 64, 0, stream>>>(F8b, 128, hop3b, 128, nullptr, 0, offs, ep);
    k_gemm_mfma<<<gg, 256, 0, stream>>>(hop2b, 128, hop3b, 128, xb, 128, xb, 128, 0,
                                        W1T + 2 * W1Q, W1T + 3 * W1Q, W1T, W1T, 128, H1, 512,
                                        NN, 512, 256, 128, b1, 1, 2);
    k_colstats<<<cdiv(NN, 64), 256, 0, stream>>>(H1, 512, stats);
    k_gnorm<<<NN, 256, 0, stream>>>(H1, 512, stats, g1w, g1b, g1a);

    // ---- layer 2: Y = sum_k (A^k h1) W2[k], K-chunked by 128.
    // hop1/hop3 fp8; hop2 bf16 parked in the chunk's own dead h1 slice.
    // Chunks >= 1: h1c pre-converted to fp8 parked in the PREVIOUS chunk's dead slice,
    // so the first gather also runs at fp8 width.
    for (int c = 0; c < 4; ++c) {
        u16* h1c = H1 + 128 * c;        // ld 512
        const u16* Wc = W2T + 128 * c;  // in-offset within transposed rows
        if (c == 0) {
            k_prop_t<0, 0, 1><<<NN, 64, 0, stream>>>(h1c, 512, nullptr, 0, F8a, 128, offs, ep);
        } else {
            unsigned char* h8 = (unsigned char*)(H1 + 128 * (c - 1));  // dead slice, ld 1024 B
            k_cvt8s<<<cdiv(NN * 64, 256), 256, 0, stream>>>(h1c, 512, h8, 1024);
            k_prop_t<1, 0, 1><<<NN, 64, 0, stream>>>(h8, 1024, nullptr, 0, F8a, 128, offs, ep);
        }
        k_gemm_mfma<<<gg, 256, 0, stream>>>(h1c, 512, F8a, 128, h1c, 512, h1c, 512, 2, Wc,
                                            Wc + WQ, Wc, Wc, 512, Y, 512, NN, 512, 256, 128,
                                            nullptr, 0, c == 0 ? 1 : 2);
        k_prop_t<1, 1, 1><<<NN, 64, 0, stream>>>(F8a, 128, h1c, 512, F8b, 128, offs, ep);
        k_prop_t<1, 0, 1><<<NN, 64, 0, stream>>>(F8b, 128, nullptr, 0, F8a, 128, offs, ep);
        k_gemm_mfma<<<gg, 256, 0, stream>>>(h1c, 512, F8a, 128, h1c, 512, h1c, 512, 2,
                                            Wc + 2 * WQ, Wc + 3 * WQ, Wc, Wc, 512, Y, 512, NN,
                                            512, 256, 128, (c == 3) ? b2 : nullptr,
                                            c == 3 ? 1 : 0, 2);
    }
    k_colstats<<<cdiv(NN, 64), 256, 0, stream>>>(Y, 512, stats + 1024);
    k_gnorm<<<NN, 256, 0, stream>>>(Y, 512, stats + 1024, g2w, g2b, g2a);

    // ---- layer 3 (Horner at width 16): G = h2 @ [W3_0|W3_1|W3_2|W3_3] (fp32, in H1 space)
    float* G = (float*)H1;             // N x 64 fp32 = 25.6 MB
    float* tA = (float*)XF;            // N x 16 fp32 = 6.4 MB
    float* tB = tA + (size_t)NN * 16;  // 6.4 MB (XF holds both)
    {
        dim3 g3(1, cdiv(NN, 128));
        k_gemm_mfma<<<g3, 256, 0, stream>>>(Y, 512, Y, 512, Y, 512, Y, 512, 0, W3T, W3T, W3T,
                                            W3T, 512, G, 64, NN, 64, 512, 512, nullptr, 0, 0);
    }
    k_prop16<<<cdiv(NN, 16), 256, 0, stream>>>(G + 48, 64, G + 32, 64, tA, nullptr, offs, ep);
    k_prop16<<<cdiv(NN, 16), 256, 0, stream>>>(tA, 16, G + 16, 64, tB, nullptr, offs, ep);
    k_prop16<<<cdiv(NN, 16), 256, 0, stream>>>(tB, 16, G + 0, 64, (float*)d_out, b3, offs, ep);
}

// Round 11
// 3305.872 us; speedup vs baseline: 1.1164x; 1.1164x over previous
//
#include <hip/hip_runtime.h>

#define NN 100000
#define EE 3200000
#define EPSF 1e-5f

typedef unsigned short u16;
typedef short bf16x8 __attribute__((ext_vector_type(8)));
typedef float f32x4 __attribute__((ext_vector_type(4)));

static inline int cdiv(int a, int b) { return (a + b - 1) / b; }

__device__ __forceinline__ float b2f(u16 u) {
    return __uint_as_float((unsigned int)u << 16);
}
__device__ __forceinline__ u16 f2b(float f) {
    unsigned int i = __float_as_uint(f);
    return (u16)((i + 0x7FFFu + ((i >> 16) & 1u)) >> 16);  // RNE
}
// packed edge: [31:17] = positive float top bits, [16:0] = src index
__device__ __forceinline__ int ep_src(unsigned int p) { return (int)(p & 0x1FFFFu); }
__device__ __forceinline__ float ep_w(unsigned int p) {
    return __uint_as_float(p & 0xFFFE0000u);
}

// ---------------- zero-init (graph-capture-safe) ----------------
__global__ void k_init(int* __restrict__ deg, int* __restrict__ cursor,
                       float* __restrict__ stats) {
    int i = blockIdx.x * 256 + threadIdx.x;
    if (i < NN) {
        deg[i] = 0;
        cursor[i] = 0;
    }
    if (i < 2048) stats[i] = 0.f;
}

// ---------------- degree histogram ----------------
__global__ void k_deg(const int* __restrict__ col, int* __restrict__ deg) {
    int i = blockIdx.x * 256 + threadIdx.x;
    if (i < EE) atomicAdd(&deg[col[i]], 1);
}

__global__ void k_dinv(const int* __restrict__ deg, float* __restrict__ dinv) {
    int i = blockIdx.x * 256 + threadIdx.x;
    if (i < NN) {
        int d = deg[i];
        dinv[i] = d > 0 ? rsqrtf((float)d) : 0.f;
    }
}

// ------- exclusive scan: 1024 threads, 98 contiguous elems per thread -------
__global__ void k_scan(const int* __restrict__ deg, int* __restrict__ offs) {
    __shared__ int sh[1024];
    int tid = threadIdx.x;
    int start = tid * 98;
    int end = min(start + 98, NN);
    int sum = 0;
    for (int i = start; i < end; ++i) sum += deg[i];
    sh[tid] = sum;
    __syncthreads();
    for (int off = 1; off < 1024; off <<= 1) {
        int t = (tid >= off) ? sh[tid - off] : 0;
        __syncthreads();
        sh[tid] += t;
        __syncthreads();
    }
    int base = tid ? sh[tid - 1] : 0;
    for (int i = start; i < end; ++i) {
        offs[i] = base;
        base += deg[i];
    }
    if (tid == 1023) offs[NN] = sh[1023];
}

// ---------------- CSR scatter: pack (w:15 | src:17) into one u32 ----------------
__global__ void k_scatter(const int* __restrict__ row, const int* __restrict__ col,
                          const float* __restrict__ dinv, const int* __restrict__ offs,
                          int* __restrict__ cursor, unsigned int* __restrict__ ep) {
    int i = blockIdx.x * 256 + threadIdx.x;
    if (i < EE) {
        int c = col[i], r = row[i];
        int pos = offs[c] + atomicAdd(&cursor[c], 1);
        float w = dinv[r] * dinv[c];  // >= 0
        unsigned int u = __float_as_uint(w);
        unsigned int rb = (u + 0xFFFFu + ((u >> 17) & 1u)) & 0xFFFE0000u;  // RNE @ 7-bit man
        ep[pos] = rb | (unsigned int)r;
    }
}

// ---------------- convert fp32 array -> bf16 (n4 = count of float4s) ----------------
__global__ void k_cvt(const float* __restrict__ src, u16* __restrict__ dst, int n4) {
    int idx = blockIdx.x * 256 + threadIdx.x;
    if (idx >= n4) return;
    float4 v = ((const float4*)src)[idx];
    ushort4 o;
    o.x = f2b(v.x);
    o.y = f2b(v.y);
    o.z = f2b(v.z);
    o.w = f2b(v.w);
    ((ushort4*)dst)[idx] = o;
}

// ---- gather propagation, width 128, 64 thr/node, 4x unroll.
// S8: source fp8 (ldin in bytes) else bf16 (ldin in elems).
// OB: write bf16 out; O8: write fp8 out. ----
template <int S8, int OB, int O8>
__global__ void k_prop_t(const void* __restrict__ in, int ldin, u16* __restrict__ outb,
                         int ldob, unsigned char* __restrict__ out8, int ldo8,
                         const int* __restrict__ offs, const unsigned int* __restrict__ ep) {
    int node = blockIdx.x;
    int f2 = threadIdx.x << 1;
    int s = offs[node], e = offs[node + 1];
    const u16* inb = (const u16*)in;
    const unsigned char* in8 = (const unsigned char*)in;
    float a0 = 0.f, a1 = 0.f;
    int t = s;
    for (; t + 4 <= e; t += 4) {
        unsigned int p0 = ep[t], p1 = ep[t + 1], p2 = ep[t + 2], p3 = ep[t + 3];
        float x0, y0, x1, y1, x2, y2, x3, y3;
        if (S8) {
            uchar2 c0 = *(const uchar2*)(in8 + (size_t)ep_src(p0) * ldin + f2);
            uchar2 c1 = *(const uchar2*)(in8 + (size_t)ep_src(p1) * ldin + f2);
            uchar2 c2 = *(const uchar2*)(in8 + (size_t)ep_src(p2) * ldin + f2);
            uchar2 c3 = *(const uchar2*)(in8 + (size_t)ep_src(p3) * ldin + f2);
            int w0 = c0.x | (c0.y << 8), w1 = c1.x | (c1.y << 8);
            int w2 = c2.x | (c2.y << 8), w3 = c3.x | (c3.y << 8);
            x0 = __builtin_amdgcn_cvt_f32_fp8(w0, 0);
            y0 = __builtin_amdgcn_cvt_f32_fp8(w0, 1);
            x1 = __builtin_amdgcn_cvt_f32_fp8(w1, 0);
            y1 = __builtin_amdgcn_cvt_f32_fp8(w1, 1);
            x2 = __builtin_amdgcn_cvt_f32_fp8(w2, 0);
            y2 = __builtin_amdgcn_cvt_f32_fp8(w2, 1);
            x3 = __builtin_amdgcn_cvt_f32_fp8(w3, 0);
            y3 = __builtin_amdgcn_cvt_f32_fp8(w3, 1);
        } else {
            ushort2 v0 = *(const ushort2*)(inb + (size_t)ep_src(p0) * ldin + f2);
            ushort2 v1 = *(const ushort2*)(inb + (size_t)ep_src(p1) * ldin + f2);
            ushort2 v2 = *(const ushort2*)(inb + (size_t)ep_src(p2) * ldin + f2);
            ushort2 v3 = *(const ushort2*)(inb + (size_t)ep_src(p3) * ldin + f2);
            x0 = b2f(v0.x);
            y0 = b2f(v0.y);
            x1 = b2f(v1.x);
            y1 = b2f(v1.y);
            x2 = b2f(v2.x);
            y2 = b2f(v2.y);
            x3 = b2f(v3.x);
            y3 = b2f(v3.y);
        }
        float w0 = ep_w(p0), w1 = ep_w(p1), w2 = ep_w(p2), w3 = ep_w(p3);
        a0 = fmaf(w0, x0, a0);
        a1 = fmaf(w0, y0, a1);
        a0 = fmaf(w1, x1, a0);
        a1 = fmaf(w1, y1, a1);
        a0 = fmaf(w2, x2, a0);
        a1 = fmaf(w2, y2, a1);
        a0 = fmaf(w3, x3, a0);
        a1 = fmaf(w3, y3, a1);
    }
    for (; t < e; ++t) {
        unsigned int p0 = ep[t];
        float x0, y0;
        if (S8) {
            uchar2 c0 = *(const uchar2*)(in8 + (size_t)ep_src(p0) * ldin + f2);
            int w = c0.x | (c0.y << 8);
            x0 = __builtin_amdgcn_cvt_f32_fp8(w, 0);
            y0 = __builtin_amdgcn_cvt_f32_fp8(w, 1);
        } else {
            ushort2 v0 = *(const ushort2*)(inb + (size_t)ep_src(p0) * ldin + f2);
            x0 = b2f(v0.x);
            y0 = b2f(v0.y);
        }
        float w0 = ep_w(p0);
        a0 = fmaf(w0, x0, a0);
        a1 = fmaf(w0, y0, a1);
    }
    if (OB) {
        ushort2 o;
        o.x = f2b(a0);
        o.y = f2b(a1);
        *(ushort2*)(outb + (size_t)node * ldob + f2) = o;
    }
    if (O8) {
        int pk = __builtin_amdgcn_cvt_pk_fp8_f32(a0, a1, 0, false);
        uchar2 o8;
        o8.x = (unsigned char)(pk & 0xFF);
        o8.y = (unsigned char)((pk >> 8) & 0xFF);
        *(uchar2*)(out8 + (size_t)node * ldo8 + f2) = o8;
    }
}

// ---- width-16 fp32 propagation with addend (Horner), 16 nodes/block, 8x unroll ----
__global__ void k_prop16(const float* __restrict__ in, int ldin,
                         const float* __restrict__ add, int ldadd,
                         float* __restrict__ out, const float* __restrict__ bias,
                         const int* __restrict__ offs, const unsigned int* __restrict__ ep) {
    int node = blockIdx.x * 16 + (threadIdx.x >> 4);
    if (node >= NN) return;
    int f = threadIdx.x & 15;
    float acc = add[(size_t)node * ldadd + f];
    int s = offs[node], e = offs[node + 1];
    int t = s;
    for (; t + 8 <= e; t += 8) {
        unsigned int p[8];
        float v[8];
#pragma unroll
        for (int u = 0; u < 8; ++u) p[u] = ep[t + u];
#pragma unroll
        for (int u = 0; u < 8; ++u) v[u] = in[(size_t)ep_src(p[u]) * ldin + f];
#pragma unroll
        for (int u = 0; u < 8; ++u) acc = fmaf(ep_w(p[u]), v[u], acc);
    }
    for (; t < e; ++t) {
        unsigned int p0 = ep[t];
        acc = fmaf(ep_w(p0), in[(size_t)ep_src(p0) * ldin + f], acc);
    }
    if (bias) acc += bias[f];
    out[node * 16 + f] = acc;
}

// ---- MFMA bf16 GEMM, 128x64 tile, up to 4 A/B sources (K quarters of Kq).
// A sources bf16 (lda in elems) or fp8 e4m3 (lda in bytes) per a8mask bit.
// B bf16 TRANSPOSED: B[n][k], stride ldb.
// cmode: 0 = write fp32, 1 = write bf16 fresh, 2 = accumulate into bf16 C ----
#define LDS_LD 40
__global__ __launch_bounds__(256) void k_gemm_mfma(
    const void* __restrict__ A0, int lda0, const void* __restrict__ A1, int lda1,
    const void* __restrict__ A2, int lda2, const void* __restrict__ A3, int lda3, int a8mask,
    const u16* __restrict__ B0, const u16* __restrict__ B1, const u16* __restrict__ B2,
    const u16* __restrict__ B3, int ldb, void* __restrict__ Cv, int ldc, int M, int Ktot,
    int Kq, const float* __restrict__ bias, int relu, int cmode) {
    __shared__ u16 As[128 * LDS_LD];
    __shared__ u16 Bs[64 * LDS_LD];
    int tid = threadIdx.x;
    int wave = tid >> 6, lane = tid & 63;
    int quad = lane >> 4, lq = lane & 15;
    int m0 = blockIdx.y * 128, n0 = blockIdx.x * 64;
    f32x4 acc[2][4] = {};

    for (int ks = 0; ks < Ktot; ks += 32) {
        int src = ks / Kq;
        int kk = ks - src * Kq;
        const void* Ap = src == 0 ? A0 : src == 1 ? A1 : src == 2 ? A2 : A3;
        int lda = src == 0 ? lda0 : src == 1 ? lda1 : src == 2 ? lda2 : lda3;
        const u16* Bp = src == 0 ? B0 : src == 1 ? B1 : src == 2 ? B2 : B3;
        if ((a8mask >> src) & 1) {
            const unsigned char* A8 = (const unsigned char*)Ap;
#pragma unroll
            for (int i = 0; i < 2; ++i) {
                int s = tid + i * 256;
                int r = s >> 2, ko = (s & 3) << 3;
                int gr = m0 + r;
                if (gr > M - 1) gr = M - 1;
                uint2 w = *(const uint2*)(A8 + (size_t)gr * lda + kk + ko);
                ushort h0 = f2b(__builtin_amdgcn_cvt_f32_fp8((int)w.x, 0));
                ushort h1 = f2b(__builtin_amdgcn_cvt_f32_fp8((int)w.x, 1));
                ushort h2 = f2b(__builtin_amdgcn_cvt_f32_fp8((int)w.x, 2));
                ushort h3 = f2b(__builtin_amdgcn_cvt_f32_fp8((int)w.x, 3));
                ushort h4 = f2b(__builtin_amdgcn_cvt_f32_fp8((int)w.y, 0));
                ushort h5 = f2b(__builtin_amdgcn_cvt_f32_fp8((int)w.y, 1));
                ushort h6 = f2b(__builtin_amdgcn_cvt_f32_fp8((int)w.y, 2));
                ushort h7 = f2b(__builtin_amdgcn_cvt_f32_fp8((int)w.y, 3));
                uint4 o;
                o.x = (unsigned)h0 | ((unsigned)h1 << 16);
                o.y = (unsigned)h2 | ((unsigned)h3 << 16);
                o.z = (unsigned)h4 | ((unsigned)h5 << 16);
                o.w = (unsigned)h6 | ((unsigned)h7 << 16);
                *(uint4*)&As[r * LDS_LD + ko] = o;
            }
        } else {
            const u16* Ab = (const u16*)Ap;
#pragma unroll
            for (int i = 0; i < 2; ++i) {
                int s = tid + i * 256;
                int r = s >> 2, ko = (s & 3) << 3;
                int gr = m0 + r;
                if (gr > M - 1) gr = M - 1;
                uint4 v = *(const uint4*)(Ab + (size_t)gr * lda + kk + ko);
                *(uint4*)&As[r * LDS_LD + ko] = v;
            }
        }
        // stage B (transposed in global): 64 n-rows x 32 k, 1 x uint4 per thread
        {
            int n = tid >> 2, ko = (tid & 3) << 3;
            uint4 v = *(const uint4*)(Bp + (size_t)(n0 + n) * ldb + kk + ko);
            *(uint4*)&Bs[n * LDS_LD + ko] = v;
        }
        __syncthreads();
        bf16x8 af[2], bfr[4];
#pragma unroll
        for (int i = 0; i < 2; ++i)
            af[i] = *(bf16x8*)&As[(wave * 32 + i * 16 + lq) * LDS_LD + quad * 8];
#pragma unroll
        for (int j = 0; j < 4; ++j)
            bfr[j] = *(bf16x8*)&Bs[(j * 16 + lq) * LDS_LD + quad * 8];
#pragma unroll
        for (int i = 0; i < 2; ++i)
#pragma unroll
            for (int j = 0; j < 4; ++j)
                acc[i][j] = __builtin_amdgcn_mfma_f32_16x16x32_bf16(af[i], bfr[j], acc[i][j],
                                                                    0, 0, 0);
        __syncthreads();
    }
#pragma unroll
    for (int i = 0; i < 2; ++i) {
#pragma unroll
        for (int j = 0; j < 4; ++j) {
            int c = n0 + j * 16 + lq;
            float bcol = bias ? bias[c] : 0.f;
            int rbase = m0 + wave * 32 + i * 16 + quad * 4;
#pragma unroll
            for (int reg = 0; reg < 4; ++reg) {
                int r = rbase + reg;
                if (r >= M) continue;
                float t = acc[i][j][reg];
                if (cmode == 2) t += b2f(*((u16*)Cv + (size_t)r * ldc + c));
                t += bcol;
                if (relu) t = fmaxf(t, 0.f);
                if (cmode == 0)
                    ((float*)Cv)[(size_t)r * ldc + c] = t;
                else
                    *((u16*)Cv + (size_t)r * ldc + c) = f2b(t);
            }
        }
    }
}

// ---------------- column stats (sum, sumsq) over bf16 NNx512 ----------------
__global__ void k_colstats(const u16* __restrict__ X, int ld, float* __restrict__ stats) {
    int r0 = blockIdx.x * 64;
    int c = threadIdx.x * 2;
    float s0 = 0, s1 = 0, q0 = 0, q1 = 0;
    int rend = min(r0 + 64, NN);
    for (int r = r0; r < rend; ++r) {
        ushort2 v = *(const ushort2*)(X + (size_t)r * ld + c);
        float x0 = b2f(v.x), x1 = b2f(v.y);
        s0 += x0;
        s1 += x1;
        q0 += x0 * x0;
        q1 += x1 * x1;
    }
    atomicAdd(&stats[c], s0);
    atomicAdd(&stats[c + 1], s1);
    atomicAdd(&stats[512 + c], q0);
    atomicAdd(&stats[512 + c + 1], q1);
}

// ---------------- graphnorm apply (in place, bf16) ----------------
__global__ void k_gnorm(u16* __restrict__ X, int ld, const float* __restrict__ stats,
                        const float* __restrict__ w, const float* __restrict__ b,
                        const float* __restrict__ a) {
    int i = blockIdx.x;
    int c = threadIdx.x * 2;
    const float invn = 1.f / NN;
    ushort2 v = *(ushort2*)(X + (size_t)i * ld + c);
    float x0 = b2f(v.x), x1 = b2f(v.y);
    {
        float m = stats[c] * invn, q = stats[512 + c] * invn, al = a[c];
        float var = q - (2.f * al - al * al) * m * m;
        x0 = (x0 - al * m) * rsqrtf(var + EPSF) * w[c] + b[c];
    }
    {
        int c1 = c + 1;
        float m = stats[c1] * invn, q = stats[512 + c1] * invn, al = a[c1];
        float var = q - (2.f * al - al * al) * m * m;
        x1 = (x1 - al * m) * rsqrtf(var + EPSF) * w[c1] + b[c1];
    }
    v.x = f2b(x0);
    v.y = f2b(x1);
    *(ushort2*)(X + (size_t)i * ld + c) = v;
}

// ---- transpose weights: src (KH, I, O) fp32 -> dst (KH, O, I) bf16 ----
__global__ void k_wt(const float* __restrict__ src, u16* __restrict__ dst, int I, int O,
                     int total) {
    int idx = blockIdx.x * 256 + threadIdx.x;
    if (idx >= total) return;
    int io = I * O;
    int k = idx / io, rem = idx - k * io;
    int n = rem / I, i = rem - n * I;
    dst[idx] = f2b(src[(size_t)k * io + (size_t)i * O + n]);
}

// ---- W3 (4,512,16) fp32 -> W3T (64, 512) bf16 : W3T[k*16+f][i] = W3[k][i][f] ----
__global__ void k_wt3(const float* __restrict__ W3, u16* __restrict__ W3T) {
    int idx = blockIdx.x * 256 + threadIdx.x;
    if (idx >= 64 * 512) return;
    int n = idx >> 9, i = idx & 511;
    int k = n >> 4, f = n & 15;
    W3T[idx] = f2b(W3[((size_t)k * 512 + i) * 16 + f]);
}

extern "C" void kernel_launch(void* const* d_in, const int* in_sizes, int n_in,
                              void* d_out, int out_size, void* d_ws, size_t ws_size,
                              hipStream_t stream) {
    const float* x = (const float*)d_in[0];
    const int* ei = (const int*)d_in[1];
    const float* W1 = (const float*)d_in[2];
    const float* b1 = (const float*)d_in[3];
    const float* W2 = (const float*)d_in[4];
    const float* b2 = (const float*)d_in[5];
    const float* W3 = (const float*)d_in[6];
    const float* b3 = (const float*)d_in[7];
    const float* g1w = (const float*)d_in[8];
    const float* g1b = (const float*)d_in[9];
    const float* g1a = (const float*)d_in[10];
    const float* g2w = (const float*)d_in[11];
    const float* g2b = (const float*)d_in[12];
    const float* g2a = (const float*)d_in[13];
    const int* row = ei;
    const int* col = ei + EE;

    char* p = (char*)d_ws;
    auto alloc = [&](size_t bytes) {
        char* r = p;
        p += (bytes + 255) & ~(size_t)255;
        return r;
    };
    // Total workspace ~247.5 MB (rounds 8-10 proven budget)
    u16* H1 = (u16*)alloc((size_t)NN * 512 * 2);                  // 102.4 MB
    u16* Y = (u16*)alloc((size_t)NN * 512 * 2);                   // 102.4 MB
    unsigned char* XF = (unsigned char*)alloc((size_t)NN * 256);  // 25.6 MB: F8a|F8b
    unsigned int* ep = (unsigned int*)alloc((size_t)EE * 4);      // 12.8 MB
    u16* W1T = (u16*)alloc((size_t)4 * 512 * 128 * 2);            // 0.5 MB
    u16* W2T = (u16*)alloc((size_t)4 * 512 * 512 * 2);            // 2.0 MB
    u16* W3T = (u16*)alloc(64 * 512 * 2);                         // 64 KB
    float* dinv = (float*)alloc((size_t)NN * 4);
    float* stats = (float*)alloc(2048 * 4);
    int* deg = (int*)alloc((size_t)NN * 4);
    int* offs = (int*)alloc((size_t)(NN + 1) * 4);
    int* cursor = (int*)alloc((size_t)NN * 4);
    (void)ws_size;
    (void)in_sizes;
    (void)n_in;
    (void)out_size;

    unsigned char* F8a = XF;
    unsigned char* F8b = XF + (size_t)NN * 128;
    // L1 bf16 scratch parked in Y (free until first L2 GEMM):
    u16* xb = Y;                        // N x 128, ld 128
    u16* hop2b = Y + (size_t)NN * 128;  // N x 128, ld 128
    u16* hop3b = Y + (size_t)2 * NN * 128;

    // ---- CSR build + weight transpose/convert
    k_init<<<cdiv(NN, 256), 256, 0, stream>>>(deg, cursor, stats);
    k_deg<<<cdiv(EE, 256), 256, 0, stream>>>(col, deg);
    k_dinv<<<cdiv(NN, 256), 256, 0, stream>>>(deg, dinv);
    k_scan<<<1, 1024, 0, stream>>>(deg, offs);
    k_scatter<<<cdiv(EE, 256), 256, 0, stream>>>(row, col, dinv, offs, cursor, ep);
    k_wt<<<cdiv(4 * 128 * 512, 256), 256, 0, stream>>>(W1, W1T, 128, 512, 4 * 128 * 512);
    k_wt<<<cdiv(4 * 512 * 512, 256), 256, 0, stream>>>(W2, W2T, 512, 512, 4 * 512 * 512);
    k_wt3<<<cdiv(64 * 512, 256), 256, 0, stream>>>(W3, W3T);

    dim3 gg(512 / 64, cdiv(NN, 128));  // (8, 782), 128x64 tiles
    const size_t WQ = (size_t)512 * 512;   // per-hop stride in W2T
    const size_t W1Q = (size_t)512 * 128;  // per-hop stride in W1T

    // ---- layer 1: H1 = sum_k (A^k x) W1[k]
    k_cvt<<<cdiv(NN * 32, 256), 256, 0, stream>>>(x, xb, NN * 32);
    k_prop_t<0, 0, 1><<<NN, 64, 0, stream>>>(xb, 128, nullptr, 0, F8a, 128, offs, ep);
    k_gemm_mfma<<<gg, 256, 0, stream>>>(xb, 128, F8a, 128, xb, 128, xb, 128, 2, W1T,
                                        W1T + W1Q, W1T, W1T, 128, H1, 512, NN, 256, 128,
                                        nullptr, 0, 1);
    k_prop_t<1, 1, 1><<<NN, 64, 0, stream>>>(F8a, 128, hop2b, 128, F8b, 128, offs, ep);
    k_prop_t<1, 1, 0><<<NN, 64, 0, stream>>>(F8b, 128, hop3b, 128, nullptr, 0, offs, ep);
    k_gemm_mfma<<<gg, 256, 0, stream>>>(hop2b, 128, hop3b, 128, xb, 128, xb, 128, 0,
                                        W1T + 2 * W1Q, W1T + 3 * W1Q, W1T, W1T, 128, H1, 512,
                                        NN, 256, 128, b1, 1, 2);
    k_colstats<<<cdiv(NN, 64), 256, 0, stream>>>(H1, 512, stats);
    k_gnorm<<<NN, 256, 0, stream>>>(H1, 512, stats, g1w, g1b, g1a);

    // ---- layer 2: Y = sum_k (A^k h1) W2[k], K-chunked by 128.
    // Chunks 0,1 (no dead slices yet): 2-GEMM split; hop1/hop3 fp8, hop2 bf16 parked in the
    // chunk's own h1 slice (dead after GEMM1 consumed it as A0).
    for (int c = 0; c < 2; ++c) {
        u16* h1c = H1 + 128 * c;        // ld 512
        const u16* Wc = W2T + 128 * c;  // in-offset within transposed rows
        k_prop_t<0, 0, 1><<<NN, 64, 0, stream>>>(h1c, 512, nullptr, 0, F8a, 128, offs, ep);
        k_gemm_mfma<<<gg, 256, 0, stream>>>(h1c, 512, F8a, 128, h1c, 512, h1c, 512, 2, Wc,
                                            Wc + WQ, Wc, Wc, 512, Y, 512, NN, 256, 128,
                                            nullptr, 0, c == 0 ? 1 : 2);
        k_prop_t<1, 1, 1><<<NN, 64, 0, stream>>>(F8a, 128, h1c, 512, F8b, 128, offs, ep);
        k_prop_t<1, 0, 1><<<NN, 64, 0, stream>>>(F8b, 128, nullptr, 0, F8a, 128, offs, ep);
        k_gemm_mfma<<<gg, 256, 0, stream>>>(h1c, 512, F8a, 128, h1c, 512, h1c, 512, 2,
                                            Wc + 2 * WQ, Wc + 3 * WQ, Wc, Wc, 512, Y, 512, NN,
                                            256, 128, nullptr, 0, 2);
    }
    // Chunks 2,3: slices 0,1 are dead -> park hop2/hop3 bf16 there; ONE K=512 GEMM each.
    for (int c = 2; c < 4; ++c) {
        u16* h1c = H1 + 128 * c;  // ld 512, alive
        u16* D2 = H1;             // dead slice 0 (ld 512)
        u16* D3 = H1 + 128;       // dead slice 1 (ld 512)
        const u16* Wc = W2T + 128 * c;
        k_prop_t<0, 0, 1><<<NN, 64, 0, stream>>>(h1c, 512, nullptr, 0, F8a, 128, offs, ep);
        k_prop_t<1, 1, 1><<<NN, 64, 0, stream>>>(F8a, 128, D2, 512, F8b, 128, offs, ep);
        k_prop_t<1, 1, 0><<<NN, 64, 0, stream>>>(F8b, 128, D3, 512, nullptr, 0, offs, ep);
        k_gemm_mfma<<<gg, 256, 0, stream>>>(h1c, 512, F8a, 128, D2, 512, D3, 512, 2, Wc,
                                            Wc + WQ, Wc + 2 * WQ, Wc + 3 * WQ, 512, Y, 512, NN,
                                            512, 128, (c == 3) ? b2 : nullptr, c == 3 ? 1 : 0,
                                            2);
    }
    k_colstats<<<cdiv(NN, 64), 256, 0, stream>>>(Y, 512, stats + 1024);
    k_gnorm<<<NN, 256, 0, stream>>>(Y, 512, stats + 1024, g2w, g2b, g2a);

    // ---- layer 3 (Horner at width 16): G = h2 @ [W3_0|W3_1|W3_2|W3_3] (fp32, in H1 space)
    float* G = (float*)H1;             // N x 64 fp32 = 25.6 MB
    float* tA = (float*)XF;            // N x 16 fp32 = 6.4 MB
    float* tB = tA + (size_t)NN * 16;  // 6.4 MB (XF holds both)
    {
        dim3 g3(1, cdiv(NN, 128));
        k_gemm_mfma<<<g3, 256, 0, stream>>>(Y, 512, Y, 512, Y, 512, Y, 512, 0, W3T, W3T, W3T,
                                            W3T, 512, G, 64, NN, 512, 512, nullptr, 0, 0);
    }
    k_prop16<<<cdiv(NN, 16), 256, 0, stream>>>(G + 48, 64, G + 32, 64, tA, nullptr, offs, ep);
    k_prop16<<<cdiv(NN, 16), 256, 0, stream>>>(tA, 16, G + 16, 64, tB, nullptr, offs, ep);
    k_prop16<<<cdiv(NN, 16), 256, 0, stream>>>(tB, 16, G + 0, 64, (float*)d_out, b3, offs, ep);
}

// Round 12
// 3277.747 us; speedup vs baseline: 1.1260x; 1.0086x over previous
//
#include <hip/hip_runtime.h>

#define NN 100000
#define EE 3200000
#define EPSF 1e-5f

typedef unsigned short u16;
typedef short bf16x8 __attribute__((ext_vector_type(8)));
typedef float f32x4 __attribute__((ext_vector_type(4)));

static inline int cdiv(int a, int b) { return (a + b - 1) / b; }

__device__ __forceinline__ float b2f(u16 u) {
    return __uint_as_float((unsigned int)u << 16);
}
__device__ __forceinline__ u16 f2b(float f) {
    unsigned int i = __float_as_uint(f);
    return (u16)((i + 0x7FFFu + ((i >> 16) & 1u)) >> 16);  // RNE
}
// packed edge: [31:17] = positive float top bits, [16:0] = src index
__device__ __forceinline__ int ep_src(unsigned int p) { return (int)(p & 0x1FFFFu); }
__device__ __forceinline__ float ep_w(unsigned int p) {
    return __uint_as_float(p & 0xFFFE0000u);
}

// ---------------- zero-init (graph-capture-safe) ----------------
__global__ void k_init(int* __restrict__ deg, int* __restrict__ cursor,
                       float* __restrict__ stats) {
    int i = blockIdx.x * 256 + threadIdx.x;
    if (i < NN) {
        deg[i] = 0;
        cursor[i] = 0;
    }
    if (i < 2048) stats[i] = 0.f;
}

// ---------------- degree histogram ----------------
__global__ void k_deg(const int* __restrict__ col, int* __restrict__ deg) {
    int i = blockIdx.x * 256 + threadIdx.x;
    if (i < EE) atomicAdd(&deg[col[i]], 1);
}

__global__ void k_dinv(const int* __restrict__ deg, float* __restrict__ dinv) {
    int i = blockIdx.x * 256 + threadIdx.x;
    if (i < NN) {
        int d = deg[i];
        dinv[i] = d > 0 ? rsqrtf((float)d) : 0.f;
    }
}

// ------- exclusive scan: 1024 threads, 98 contiguous elems per thread -------
__global__ void k_scan(const int* __restrict__ deg, int* __restrict__ offs) {
    __shared__ int sh[1024];
    int tid = threadIdx.x;
    int start = tid * 98;
    int end = min(start + 98, NN);
    int sum = 0;
    for (int i = start; i < end; ++i) sum += deg[i];
    sh[tid] = sum;
    __syncthreads();
    for (int off = 1; off < 1024; off <<= 1) {
        int t = (tid >= off) ? sh[tid - off] : 0;
        __syncthreads();
        sh[tid] += t;
        __syncthreads();
    }
    int base = tid ? sh[tid - 1] : 0;
    for (int i = start; i < end; ++i) {
        offs[i] = base;
        base += deg[i];
    }
    if (tid == 1023) offs[NN] = sh[1023];
}

// ---------------- CSR scatter: pack (w:15 | src:17) into one u32 ----------------
__global__ void k_scatter(const int* __restrict__ row, const int* __restrict__ col,
                          const float* __restrict__ dinv, const int* __restrict__ offs,
                          int* __restrict__ cursor, unsigned int* __restrict__ ep) {
    int i = blockIdx.x * 256 + threadIdx.x;
    if (i < EE) {
        int c = col[i], r = row[i];
        int pos = offs[c] + atomicAdd(&cursor[c], 1);
        float w = dinv[r] * dinv[c];  // >= 0
        unsigned int u = __float_as_uint(w);
        unsigned int rb = (u + 0xFFFFu + ((u >> 17) & 1u)) & 0xFFFE0000u;  // RNE @ 7-bit man
        ep[pos] = rb | (unsigned int)r;
    }
}

// ---------------- convert fp32 array -> bf16 (n4 = count of float4s) ----------------
__global__ void k_cvt(const float* __restrict__ src, u16* __restrict__ dst, int n4) {
    int idx = blockIdx.x * 256 + threadIdx.x;
    if (idx >= n4) return;
    float4 v = ((const float4*)src)[idx];
    ushort4 o;
    o.x = f2b(v.x);
    o.y = f2b(v.y);
    o.z = f2b(v.z);
    o.w = f2b(v.w);
    ((ushort4*)dst)[idx] = o;
}

// ---- gather propagation, width 128, 64 thr/node, 4x unroll.
// S8: source fp8 (ldin in bytes) else bf16 (ldin in elems).
// OB: write bf16 out; O8: write fp8 out. ----
template <int S8, int OB, int O8>
__global__ void k_prop_t(const void* __restrict__ in, int ldin, u16* __restrict__ outb,
                         int ldob, unsigned char* __restrict__ out8, int ldo8,
                         const int* __restrict__ offs, const unsigned int* __restrict__ ep) {
    int node = blockIdx.x;
    int f2 = threadIdx.x << 1;
    int s = offs[node], e = offs[node + 1];
    const u16* inb = (const u16*)in;
    const unsigned char* in8 = (const unsigned char*)in;
    float a0 = 0.f, a1 = 0.f;
    int t = s;
    for (; t + 4 <= e; t += 4) {
        unsigned int p0 = ep[t], p1 = ep[t + 1], p2 = ep[t + 2], p3 = ep[t + 3];
        float x0, y0, x1, y1, x2, y2, x3, y3;
        if (S8) {
            uchar2 c0 = *(const uchar2*)(in8 + (size_t)ep_src(p0) * ldin + f2);
            uchar2 c1 = *(const uchar2*)(in8 + (size_t)ep_src(p1) * ldin + f2);
            uchar2 c2 = *(const uchar2*)(in8 + (size_t)ep_src(p2) * ldin + f2);
            uchar2 c3 = *(const uchar2*)(in8 + (size_t)ep_src(p3) * ldin + f2);
            int w0 = c0.x | (c0.y << 8), w1 = c1.x | (c1.y << 8);
            int w2 = c2.x | (c2.y << 8), w3 = c3.x | (c3.y << 8);
            x0 = __builtin_amdgcn_cvt_f32_fp8(w0, 0);
            y0 = __builtin_amdgcn_cvt_f32_fp8(w0, 1);
            x1 = __builtin_amdgcn_cvt_f32_fp8(w1, 0);
            y1 = __builtin_amdgcn_cvt_f32_fp8(w1, 1);
            x2 = __builtin_amdgcn_cvt_f32_fp8(w2, 0);
            y2 = __builtin_amdgcn_cvt_f32_fp8(w2, 1);
            x3 = __builtin_amdgcn_cvt_f32_fp8(w3, 0);
            y3 = __builtin_amdgcn_cvt_f32_fp8(w3, 1);
        } else {
            ushort2 v0 = *(const ushort2*)(inb + (size_t)ep_src(p0) * ldin + f2);
            ushort2 v1 = *(const ushort2*)(inb + (size_t)ep_src(p1) * ldin + f2);
            ushort2 v2 = *(const ushort2*)(inb + (size_t)ep_src(p2) * ldin + f2);
            ushort2 v3 = *(const ushort2*)(inb + (size_t)ep_src(p3) * ldin + f2);
            x0 = b2f(v0.x);
            y0 = b2f(v0.y);
            x1 = b2f(v1.x);
            y1 = b2f(v1.y);
            x2 = b2f(v2.x);
            y2 = b2f(v2.y);
            x3 = b2f(v3.x);
            y3 = b2f(v3.y);
        }
        float w0 = ep_w(p0), w1 = ep_w(p1), w2 = ep_w(p2), w3 = ep_w(p3);
        a0 = fmaf(w0, x0, a0);
        a1 = fmaf(w0, y0, a1);
        a0 = fmaf(w1, x1, a0);
        a1 = fmaf(w1, y1, a1);
        a0 = fmaf(w2, x2, a0);
        a1 = fmaf(w2, y2, a1);
        a0 = fmaf(w3, x3, a0);
        a1 = fmaf(w3, y3, a1);
    }
    for (; t < e; ++t) {
        unsigned int p0 = ep[t];
        float x0, y0;
        if (S8) {
            uchar2 c0 = *(const uchar2*)(in8 + (size_t)ep_src(p0) * ldin + f2);
            int w = c0.x | (c0.y << 8);
            x0 = __builtin_amdgcn_cvt_f32_fp8(w, 0);
            y0 = __builtin_amdgcn_cvt_f32_fp8(w, 1);
        } else {
            ushort2 v0 = *(const ushort2*)(inb + (size_t)ep_src(p0) * ldin + f2);
            x0 = b2f(v0.x);
            y0 = b2f(v0.y);
        }
        float w0 = ep_w(p0);
        a0 = fmaf(w0, x0, a0);
        a1 = fmaf(w0, y0, a1);
    }
    if (OB) {
        ushort2 o;
        o.x = f2b(a0);
        o.y = f2b(a1);
        *(ushort2*)(outb + (size_t)node * ldob + f2) = o;
    }
    if (O8) {
        int pk = __builtin_amdgcn_cvt_pk_fp8_f32(a0, a1, 0, false);
        uchar2 o8;
        o8.x = (unsigned char)(pk & 0xFF);
        o8.y = (unsigned char)((pk >> 8) & 0xFF);
        *(uchar2*)(out8 + (size_t)node * ldo8 + f2) = o8;
    }
}

// ---- width-16 fp32 propagation with addend (Horner), 16 nodes/block, 8x unroll ----
__global__ void k_prop16(const float* __restrict__ in, int ldin,
                         const float* __restrict__ add, int ldadd,
                         float* __restrict__ out, const float* __restrict__ bias,
                         const int* __restrict__ offs, const unsigned int* __restrict__ ep) {
    int node = blockIdx.x * 16 + (threadIdx.x >> 4);
    if (node >= NN) return;
    int f = threadIdx.x & 15;
    float acc = add[(size_t)node * ldadd + f];
    int s = offs[node], e = offs[node + 1];
    int t = s;
    for (; t + 8 <= e; t += 8) {
        unsigned int p[8];
        float v[8];
#pragma unroll
        for (int u = 0; u < 8; ++u) p[u] = ep[t + u];
#pragma unroll
        for (int u = 0; u < 8; ++u) v[u] = in[(size_t)ep_src(p[u]) * ldin + f];
#pragma unroll
        for (int u = 0; u < 8; ++u) acc = fmaf(ep_w(p[u]), v[u], acc);
    }
    for (; t < e; ++t) {
        unsigned int p0 = ep[t];
        acc = fmaf(ep_w(p0), in[(size_t)ep_src(p0) * ldin + f], acc);
    }
    if (bias) acc += bias[f];
    out[node * 16 + f] = acc;
}

// ---- MFMA bf16 GEMM, 128x64 tile, up to 4 A/B sources (K quarters of Kq).
// A sources bf16 (lda in elems) or fp8 e4m3 (lda in bytes) per a8mask bit.
// B bf16 TRANSPOSED: B[n][k], stride ldb.
// LDS XOR swizzle (1 bit): breaks the delta-8-row bank aliasing of LDS_LD=40.
// cmode: 0 = write fp32, 1 = write bf16 fresh, 2 = accumulate into bf16 C ----
#define LDS_LD 40
#define SWZ(r, ko) ((ko) ^ ((((r) >> 3) & 1) << 3))
__global__ __launch_bounds__(256) void k_gemm_mfma(
    const void* __restrict__ A0, int lda0, const void* __restrict__ A1, int lda1,
    const void* __restrict__ A2, int lda2, const void* __restrict__ A3, int lda3, int a8mask,
    const u16* __restrict__ B0, const u16* __restrict__ B1, const u16* __restrict__ B2,
    const u16* __restrict__ B3, int ldb, void* __restrict__ Cv, int ldc, int M, int Ktot,
    int Kq, const float* __restrict__ bias, int relu, int cmode) {
    __shared__ u16 As[128 * LDS_LD];
    __shared__ u16 Bs[64 * LDS_LD];
    int tid = threadIdx.x;
    int wave = tid >> 6, lane = tid & 63;
    int quad = lane >> 4, lq = lane & 15;
    int m0 = blockIdx.y * 128, n0 = blockIdx.x * 64;
    f32x4 acc[2][4] = {};

    for (int ks = 0; ks < Ktot; ks += 32) {
        int src = ks / Kq;
        int kk = ks - src * Kq;
        const void* Ap = src == 0 ? A0 : src == 1 ? A1 : src == 2 ? A2 : A3;
        int lda = src == 0 ? lda0 : src == 1 ? lda1 : src == 2 ? lda2 : lda3;
        const u16* Bp = src == 0 ? B0 : src == 1 ? B1 : src == 2 ? B2 : B3;
        if ((a8mask >> src) & 1) {
            const unsigned char* A8 = (const unsigned char*)Ap;
#pragma unroll
            for (int i = 0; i < 2; ++i) {
                int s = tid + i * 256;
                int r = s >> 2, ko = (s & 3) << 3;
                int gr = m0 + r;
                if (gr > M - 1) gr = M - 1;
                uint2 w = *(const uint2*)(A8 + (size_t)gr * lda + kk + ko);
                ushort h0 = f2b(__builtin_amdgcn_cvt_f32_fp8((int)w.x, 0));
                ushort h1 = f2b(__builtin_amdgcn_cvt_f32_fp8((int)w.x, 1));
                ushort h2 = f2b(__builtin_amdgcn_cvt_f32_fp8((int)w.x, 2));
                ushort h3 = f2b(__builtin_amdgcn_cvt_f32_fp8((int)w.x, 3));
                ushort h4 = f2b(__builtin_amdgcn_cvt_f32_fp8((int)w.y, 0));
                ushort h5 = f2b(__builtin_amdgcn_cvt_f32_fp8((int)w.y, 1));
                ushort h6 = f2b(__builtin_amdgcn_cvt_f32_fp8((int)w.y, 2));
                ushort h7 = f2b(__builtin_amdgcn_cvt_f32_fp8((int)w.y, 3));
                uint4 o;
                o.x = (unsigned)h0 | ((unsigned)h1 << 16);
                o.y = (unsigned)h2 | ((unsigned)h3 << 16);
                o.z = (unsigned)h4 | ((unsigned)h5 << 16);
                o.w = (unsigned)h6 | ((unsigned)h7 << 16);
                *(uint4*)&As[r * LDS_LD + SWZ(r, ko)] = o;
            }
        } else {
            const u16* Ab = (const u16*)Ap;
#pragma unroll
            for (int i = 0; i < 2; ++i) {
                int s = tid + i * 256;
                int r = s >> 2, ko = (s & 3) << 3;
                int gr = m0 + r;
                if (gr > M - 1) gr = M - 1;
                uint4 v = *(const uint4*)(Ab + (size_t)gr * lda + kk + ko);
                *(uint4*)&As[r * LDS_LD + SWZ(r, ko)] = v;
            }
        }
        // stage B (transposed in global): 64 n-rows x 32 k, 1 x uint4 per thread
        {
            int n = tid >> 2, ko = (tid & 3) << 3;
            uint4 v = *(const uint4*)(Bp + (size_t)(n0 + n) * ldb + kk + ko);
            *(uint4*)&Bs[n * LDS_LD + SWZ(n, ko)] = v;
        }
        __syncthreads();
        bf16x8 af[2], bfr[4];
#pragma unroll
        for (int i = 0; i < 2; ++i) {
            int r = wave * 32 + i * 16 + lq;
            af[i] = *(bf16x8*)&As[r * LDS_LD + SWZ(r, quad * 8)];
        }
#pragma unroll
        for (int j = 0; j < 4; ++j) {
            int r = j * 16 + lq;
            bfr[j] = *(bf16x8*)&Bs[r * LDS_LD + SWZ(r, quad * 8)];
        }
#pragma unroll
        for (int i = 0; i < 2; ++i)
#pragma unroll
            for (int j = 0; j < 4; ++j)
                acc[i][j] = __builtin_amdgcn_mfma_f32_16x16x32_bf16(af[i], bfr[j], acc[i][j],
                                                                    0, 0, 0);
        __syncthreads();
    }
#pragma unroll
    for (int i = 0; i < 2; ++i) {
#pragma unroll
        for (int j = 0; j < 4; ++j) {
            int c = n0 + j * 16 + lq;
            float bcol = bias ? bias[c] : 0.f;
            int rbase = m0 + wave * 32 + i * 16 + quad * 4;
#pragma unroll
            for (int reg = 0; reg < 4; ++reg) {
                int r = rbase + reg;
                if (r >= M) continue;
                float t = acc[i][j][reg];
                if (cmode == 2) t += b2f(*((u16*)Cv + (size_t)r * ldc + c));
                t += bcol;
                if (relu) t = fmaxf(t, 0.f);
                if (cmode == 0)
                    ((float*)Cv)[(size_t)r * ldc + c] = t;
                else
                    *((u16*)Cv + (size_t)r * ldc + c) = f2b(t);
            }
        }
    }
}

// ---------------- column stats (sum, sumsq) over bf16 NNx512 ----------------
__global__ void k_colstats(const u16* __restrict__ X, int ld, float* __restrict__ stats) {
    int r0 = blockIdx.x * 64;
    int c = threadIdx.x * 2;
    float s0 = 0, s1 = 0, q0 = 0, q1 = 0;
    int rend = min(r0 + 64, NN);
    for (int r = r0; r < rend; ++r) {
        ushort2 v = *(const ushort2*)(X + (size_t)r * ld + c);
        float x0 = b2f(v.x), x1 = b2f(v.y);
        s0 += x0;
        s1 += x1;
        q0 += x0 * x0;
        q1 += x1 * x1;
    }
    atomicAdd(&stats[c], s0);
    atomicAdd(&stats[c + 1], s1);
    atomicAdd(&stats[512 + c], q0);
    atomicAdd(&stats[512 + c + 1], q1);
}

// ---------------- graphnorm apply (in place, bf16) ----------------
__global__ void k_gnorm(u16* __restrict__ X, int ld, const float* __restrict__ stats,
                        const float* __restrict__ w, const float* __restrict__ b,
                        const float* __restrict__ a) {
    int i = blockIdx.x;
    int c = threadIdx.x * 2;
    const float invn = 1.f / NN;
    ushort2 v = *(ushort2*)(X + (size_t)i * ld + c);
    float x0 = b2f(v.x), x1 = b2f(v.y);
    {
        float m = stats[c] * invn, q = stats[512 + c] * invn, al = a[c];
        float var = q - (2.f * al - al * al) * m * m;
        x0 = (x0 - al * m) * rsqrtf(var + EPSF) * w[c] + b[c];
    }
    {
        int c1 = c + 1;
        float m = stats[c1] * invn, q = stats[512 + c1] * invn, al = a[c1];
        float var = q - (2.f * al - al * al) * m * m;
        x1 = (x1 - al * m) * rsqrtf(var + EPSF) * w[c1] + b[c1];
    }
    v.x = f2b(x0);
    v.y = f2b(x1);
    *(ushort2*)(X + (size_t)i * ld + c) = v;
}

// ---- transpose weights: src (KH, I, O) fp32 -> dst (KH, O, I) bf16 ----
__global__ void k_wt(const float* __restrict__ src, u16* __restrict__ dst, int I, int O,
                     int total) {
    int idx = blockIdx.x * 256 + threadIdx.x;
    if (idx >= total) return;
    int io = I * O;
    int k = idx / io, rem = idx - k * io;
    int n = rem / I, i = rem - n * I;
    dst[idx] = f2b(src[(size_t)k * io + (size_t)i * O + n]);
}

// ---- W3 (4,512,16) fp32 -> W3T (64, 512) bf16 : W3T[k*16+f][i] = W3[k][i][f] ----
__global__ void k_wt3(const float* __restrict__ W3, u16* __restrict__ W3T) {
    int idx = blockIdx.x * 256 + threadIdx.x;
    if (idx >= 64 * 512) return;
    int n = idx >> 9, i = idx & 511;
    int k = n >> 4, f = n & 15;
    W3T[idx] = f2b(W3[((size_t)k * 512 + i) * 16 + f]);
}

extern "C" void kernel_launch(void* const* d_in, const int* in_sizes, int n_in,
                              void* d_out, int out_size, void* d_ws, size_t ws_size,
                              hipStream_t stream) {
    const float* x = (const float*)d_in[0];
    const int* ei = (const int*)d_in[1];
    const float* W1 = (const float*)d_in[2];
    const float* b1 = (const float*)d_in[3];
    const float* W2 = (const float*)d_in[4];
    const float* b2 = (const float*)d_in[5];
    const float* W3 = (const float*)d_in[6];
    const float* b3 = (const float*)d_in[7];
    const float* g1w = (const float*)d_in[8];
    const float* g1b = (const float*)d_in[9];
    const float* g1a = (const float*)d_in[10];
    const float* g2w = (const float*)d_in[11];
    const float* g2b = (const float*)d_in[12];
    const float* g2a = (const float*)d_in[13];
    const int* row = ei;
    const int* col = ei + EE;

    char* p = (char*)d_ws;
    auto alloc = [&](size_t bytes) {
        char* r = p;
        p += (bytes + 255) & ~(size_t)255;
        return r;
    };
    // Total workspace ~247.5 MB (rounds 8-11 proven budget)
    u16* H1 = (u16*)alloc((size_t)NN * 512 * 2);                  // 102.4 MB
    u16* Y = (u16*)alloc((size_t)NN * 512 * 2);                   // 102.4 MB
    unsigned char* XF = (unsigned char*)alloc((size_t)NN * 256);  // 25.6 MB: F8a|F8b
    unsigned int* ep = (unsigned int*)alloc((size_t)EE * 4);      // 12.8 MB
    u16* W1T = (u16*)alloc((size_t)4 * 512 * 128 * 2);            // 0.5 MB
    u16* W2T = (u16*)alloc((size_t)4 * 512 * 512 * 2);            // 2.0 MB
    u16* W3T = (u16*)alloc(64 * 512 * 2);                         // 64 KB
    float* dinv = (float*)alloc((size_t)NN * 4);
    float* stats = (float*)alloc(2048 * 4);
    int* deg = (int*)alloc((size_t)NN * 4);
    int* offs = (int*)alloc((size_t)(NN + 1) * 4);
    int* cursor = (int*)alloc((size_t)NN * 4);
    (void)ws_size;
    (void)in_sizes;
    (void)n_in;
    (void)out_size;

    unsigned char* F8a = XF;
    unsigned char* F8b = XF + (size_t)NN * 128;
    u16* xb = Y;  // N x 128 bf16 (ld 128) parked in Y; dead before L2 GEMM1 writes Y

    // ---- CSR build + weight transpose/convert
    k_init<<<cdiv(NN, 256), 256, 0, stream>>>(deg, cursor, stats);
    k_deg<<<cdiv(EE, 256), 256, 0, stream>>>(col, deg);
    k_dinv<<<cdiv(NN, 256), 256, 0, stream>>>(deg, dinv);
    k_scan<<<1, 1024, 0, stream>>>(deg, offs);
    k_scatter<<<cdiv(EE, 256), 256, 0, stream>>>(row, col, dinv, offs, cursor, ep);
    k_wt<<<cdiv(4 * 128 * 512, 256), 256, 0, stream>>>(W1, W1T, 128, 512, 4 * 128 * 512);
    k_wt<<<cdiv(4 * 512 * 512, 256), 256, 0, stream>>>(W2, W2T, 512, 512, 4 * 512 * 512);
    k_wt3<<<cdiv(64 * 512, 256), 256, 0, stream>>>(W3, W3T);

    dim3 gg(512 / 64, cdiv(NN, 128));  // (8, 782), 128x64 tiles
    const size_t WQ = (size_t)512 * 512;   // per-hop stride in W2T
    const size_t W1Q = (size_t)512 * 128;  // per-hop stride in W1T

    // ---- layer 1: H1 = sum_k (A^k x) W1[k]; hops 2,3 stay fp8 end-to-end
    k_cvt<<<cdiv(NN * 32, 256), 256, 0, stream>>>(x, xb, NN * 32);
    k_prop_t<0, 0, 1><<<NN, 64, 0, stream>>>(xb, 128, nullptr, 0, F8a, 128, offs, ep);
    k_gemm_mfma<<<gg, 256, 0, stream>>>(xb, 128, F8a, 128, xb, 128, xb, 128, 2, W1T,
                                        W1T + W1Q, W1T, W1T, 128, H1, 512, NN, 256, 128,
                                        nullptr, 0, 1);
    k_prop_t<1, 0, 1><<<NN, 64, 0, stream>>>(F8a, 128, nullptr, 0, F8b, 128, offs, ep);
    k_prop_t<1, 0, 1><<<NN, 64, 0, stream>>>(F8b, 128, nullptr, 0, F8a, 128, offs, ep);
    k_gemm_mfma<<<gg, 256, 0, stream>>>(F8b, 128, F8a, 128, xb, 128, xb, 128, 3,
                                        W1T + 2 * W1Q, W1T + 3 * W1Q, W1T, W1T, 128, H1, 512,
                                        NN, 256, 128, b1, 1, 2);
    k_colstats<<<cdiv(NN, 64), 256, 0, stream>>>(H1, 512, stats);
    k_gnorm<<<NN, 256, 0, stream>>>(H1, 512, stats, g1w, g1b, g1a);

    // ---- layer 2: Y = sum_k (A^k h1) W2[k], K-chunked by 128. Hops fp8 end-to-end.
    // Chunks 0,1: 2-GEMM split (no dead slices yet).
    for (int c = 0; c < 2; ++c) {
        u16* h1c = H1 + 128 * c;        // ld 512
        const u16* Wc = W2T + 128 * c;  // in-offset within transposed rows
        k_prop_t<0, 0, 1><<<NN, 64, 0, stream>>>(h1c, 512, nullptr, 0, F8a, 128, offs, ep);
        k_gemm_mfma<<<gg, 256, 0, stream>>>(h1c, 512, F8a, 128, h1c, 512, h1c, 512, 2, Wc,
                                            Wc + WQ, Wc, Wc, 512, Y, 512, NN, 256, 128,
                                            nullptr, 0, c == 0 ? 1 : 2);
        k_prop_t<1, 0, 1><<<NN, 64, 0, stream>>>(F8a, 128, nullptr, 0, F8b, 128, offs, ep);
        k_prop_t<1, 0, 1><<<NN, 64, 0, stream>>>(F8b, 128, nullptr, 0, F8a, 128, offs, ep);
        k_gemm_mfma<<<gg, 256, 0, stream>>>(F8b, 128, F8a, 128, h1c, 512, h1c, 512, 3,
                                            Wc + 2 * WQ, Wc + 3 * WQ, Wc, Wc, 512, Y, 512, NN,
                                            256, 128, nullptr, 0, 2);
    }
    // Chunks 2,3: hop3 parked fp8 in dead H1 slice 0 -> ONE K=512 GEMM each.
    for (int c = 2; c < 4; ++c) {
        u16* h1c = H1 + 128 * c;                    // ld 512, alive
        unsigned char* F8c = (unsigned char*)H1;    // dead slice 0, fp8 ld 1024 B
        const u16* Wc = W2T + 128 * c;
        k_prop_t<0, 0, 1><<<NN, 64, 0, stream>>>(h1c, 512, nullptr, 0, F8a, 128, offs, ep);
        k_prop_t<1, 0, 1><<<NN, 64, 0, stream>>>(F8a, 128, nullptr, 0, F8b, 128, offs, ep);
        k_prop_t<1, 0, 1><<<NN, 64, 0, stream>>>(F8b, 128, nullptr, 0, F8c, 1024, offs, ep);
        k_gemm_mfma<<<gg, 256, 0, stream>>>(h1c, 512, F8a, 128, F8b, 128, F8c, 1024, 14, Wc,
                                            Wc + WQ, Wc + 2 * WQ, Wc + 3 * WQ, 512, Y, 512, NN,
                                            512, 128, (c == 3) ? b2 : nullptr, c == 3 ? 1 : 0,
                                            2);
    }
    k_colstats<<<cdiv(NN, 64), 256, 0, stream>>>(Y, 512, stats + 1024);
    k_gnorm<<<NN, 256, 0, stream>>>(Y, 512, stats + 1024, g2w, g2b, g2a);

    // ---- layer 3 (Horner at width 16): G = h2 @ [W3_0|W3_1|W3_2|W3_3] (fp32, in H1 space)
    float* G = (float*)H1;             // N x 64 fp32 = 25.6 MB
    float* tA = (float*)XF;            // N x 16 fp32 = 6.4 MB
    float* tB = tA + (size_t)NN * 16;  // 6.4 MB (XF holds both)
    {
        dim3 g3(1, cdiv(NN, 128));
        k_gemm_mfma<<<g3, 256, 0, stream>>>(Y, 512, Y, 512, Y, 512, Y, 512, 0, W3T, W3T, W3T,
                                            W3T, 512, G, 64, NN, 512, 512, nullptr, 0, 0);
    }
    k_prop16<<<cdiv(NN, 16), 256, 0, stream>>>(G + 48, 64, G + 32, 64, tA, nullptr, offs, ep);
    k_prop16<<<cdiv(NN, 16), 256, 0, stream>>>(tA, 16, G + 16, 64, tB, nullptr, offs, ep);
    k_prop16<<<cdiv(NN, 16), 256, 0, stream>>>(tB, 16, G + 0, 64, (float*)d_out, b3, offs, ep);
}

// Round 13
// 3228.825 us; speedup vs baseline: 1.1431x; 1.0152x over previous
//
#include <hip/hip_runtime.h>

#define NN 100000
#define EE 3200000
#define EPSF 1e-5f

typedef unsigned short u16;
typedef short bf16x8 __attribute__((ext_vector_type(8)));
typedef float f32x4 __attribute__((ext_vector_type(4)));

static inline int cdiv(int a, int b) { return (a + b - 1) / b; }

__device__ __forceinline__ float b2f(u16 u) {
    return __uint_as_float((unsigned int)u << 16);
}
__device__ __forceinline__ u16 f2b(float f) {
    unsigned int i = __float_as_uint(f);
    return (u16)((i + 0x7FFFu + ((i >> 16) & 1u)) >> 16);  // RNE
}
// packed edge: [31:17] = positive float top bits, [16:0] = src index
__device__ __forceinline__ int ep_src(unsigned int p) { return (int)(p & 0x1FFFFu); }
__device__ __forceinline__ float ep_w(unsigned int p) {
    return __uint_as_float(p & 0xFFFE0000u);
}
// pack high16(f0) | high16(f1)<<16 — exact bf16 for values exactly representable (fp8 set)
__device__ __forceinline__ unsigned pkhi(float f0, float f1) {
    return __builtin_amdgcn_perm(__float_as_uint(f1), __float_as_uint(f0), 0x07060302u);
}

// ---------------- zero-init (graph-capture-safe) ----------------
__global__ void k_init(int* __restrict__ deg, int* __restrict__ cursor,
                       float* __restrict__ stats) {
    int i = blockIdx.x * 256 + threadIdx.x;
    if (i < NN) {
        deg[i] = 0;
        cursor[i] = 0;
    }
    if (i < 2048) stats[i] = 0.f;
}

// ---------------- degree histogram ----------------
__global__ void k_deg(const int* __restrict__ col, int* __restrict__ deg) {
    int i = blockIdx.x * 256 + threadIdx.x;
    if (i < EE) atomicAdd(&deg[col[i]], 1);
}

__global__ void k_dinv(const int* __restrict__ deg, float* __restrict__ dinv) {
    int i = blockIdx.x * 256 + threadIdx.x;
    if (i < NN) {
        int d = deg[i];
        dinv[i] = d > 0 ? rsqrtf((float)d) : 0.f;
    }
}

// ------- exclusive scan: 1024 threads, 98 contiguous elems per thread -------
__global__ void k_scan(const int* __restrict__ deg, int* __restrict__ offs) {
    __shared__ int sh[1024];
    int tid = threadIdx.x;
    int start = tid * 98;
    int end = min(start + 98, NN);
    int sum = 0;
    for (int i = start; i < end; ++i) sum += deg[i];
    sh[tid] = sum;
    __syncthreads();
    for (int off = 1; off < 1024; off <<= 1) {
        int t = (tid >= off) ? sh[tid - off] : 0;
        __syncthreads();
        sh[tid] += t;
        __syncthreads();
    }
    int base = tid ? sh[tid - 1] : 0;
    for (int i = start; i < end; ++i) {
        offs[i] = base;
        base += deg[i];
    }
    if (tid == 1023) offs[NN] = sh[1023];
}

// ---------------- CSR scatter: pack (w:15 | src:17) into one u32 ----------------
__global__ void k_scatter(const int* __restrict__ row, const int* __restrict__ col,
                          const float* __restrict__ dinv, const int* __restrict__ offs,
                          int* __restrict__ cursor, unsigned int* __restrict__ ep) {
    int i = blockIdx.x * 256 + threadIdx.x;
    if (i < EE) {
        int c = col[i], r = row[i];
        int pos = offs[c] + atomicAdd(&cursor[c], 1);
        float w = dinv[r] * dinv[c];  // >= 0
        unsigned int u = __float_as_uint(w);
        unsigned int rb = (u + 0xFFFFu + ((u >> 17) & 1u)) & 0xFFFE0000u;  // RNE @ 7-bit man
        ep[pos] = rb | (unsigned int)r;
    }
}

// ---------------- convert fp32 array -> bf16 (n4 = count of float4s) ----------------
__global__ void k_cvt(const float* __restrict__ src, u16* __restrict__ dst, int n4) {
    int idx = blockIdx.x * 256 + threadIdx.x;
    if (idx >= n4) return;
    float4 v = ((const float4*)src)[idx];
    ushort4 o;
    o.x = f2b(v.x);
    o.y = f2b(v.y);
    o.z = f2b(v.z);
    o.w = f2b(v.w);
    ((ushort4*)dst)[idx] = o;
}

// ---- gather propagation, width 128, 64 thr/node, 4x unroll.
// S8: source fp8 (ldin in bytes) else bf16 (ldin in elems).
// OB: write bf16 out; O8: write fp8 out. ----
template <int S8, int OB, int O8>
__global__ void k_prop_t(const void* __restrict__ in, int ldin, u16* __restrict__ outb,
                         int ldob, unsigned char* __restrict__ out8, int ldo8,
                         const int* __restrict__ offs, const unsigned int* __restrict__ ep) {
    int node = blockIdx.x;
    int f2 = threadIdx.x << 1;
    int s = offs[node], e = offs[node + 1];
    const u16* inb = (const u16*)in;
    const unsigned char* in8 = (const unsigned char*)in;
    float a0 = 0.f, a1 = 0.f;
    int t = s;
    for (; t + 4 <= e; t += 4) {
        unsigned int p0 = ep[t], p1 = ep[t + 1], p2 = ep[t + 2], p3 = ep[t + 3];
        float x0, y0, x1, y1, x2, y2, x3, y3;
        if (S8) {
            uchar2 c0 = *(const uchar2*)(in8 + (size_t)ep_src(p0) * ldin + f2);
            uchar2 c1 = *(const uchar2*)(in8 + (size_t)ep_src(p1) * ldin + f2);
            uchar2 c2 = *(const uchar2*)(in8 + (size_t)ep_src(p2) * ldin + f2);
            uchar2 c3 = *(const uchar2*)(in8 + (size_t)ep_src(p3) * ldin + f2);
            int w0 = c0.x | (c0.y << 8), w1 = c1.x | (c1.y << 8);
            int w2 = c2.x | (c2.y << 8), w3 = c3.x | (c3.y << 8);
            x0 = __builtin_amdgcn_cvt_f32_fp8(w0, 0);
            y0 = __builtin_amdgcn_cvt_f32_fp8(w0, 1);
            x1 = __builtin_amdgcn_cvt_f32_fp8(w1, 0);
            y1 = __builtin_amdgcn_cvt_f32_fp8(w1, 1);
            x2 = __builtin_amdgcn_cvt_f32_fp8(w2, 0);
            y2 = __builtin_amdgcn_cvt_f32_fp8(w2, 1);
            x3 = __builtin_amdgcn_cvt_f32_fp8(w3, 0);
            y3 = __builtin_amdgcn_cvt_f32_fp8(w3, 1);
        } else {
            ushort2 v0 = *(const ushort2*)(inb + (size_t)ep_src(p0) * ldin + f2);
            ushort2 v1 = *(const ushort2*)(inb + (size_t)ep_src(p1) * ldin + f2);
            ushort2 v2 = *(const ushort2*)(inb + (size_t)ep_src(p2) * ldin + f2);
            ushort2 v3 = *(const ushort2*)(inb + (size_t)ep_src(p3) * ldin + f2);
            x0 = b2f(v0.x);
            y0 = b2f(v0.y);
            x1 = b2f(v1.x);
            y1 = b2f(v1.y);
            x2 = b2f(v2.x);
            y2 = b2f(v2.y);
            x3 = b2f(v3.x);
            y3 = b2f(v3.y);
        }
        float w0 = ep_w(p0), w1 = ep_w(p1), w2 = ep_w(p2), w3 = ep_w(p3);
        a0 = fmaf(w0, x0, a0);
        a1 = fmaf(w0, y0, a1);
        a0 = fmaf(w1, x1, a0);
        a1 = fmaf(w1, y1, a1);
        a0 = fmaf(w2, x2, a0);
        a1 = fmaf(w2, y2, a1);
        a0 = fmaf(w3, x3, a0);
        a1 = fmaf(w3, y3, a1);
    }
    for (; t < e; ++t) {
        unsigned int p0 = ep[t];
        float x0, y0;
        if (S8) {
            uchar2 c0 = *(const uchar2*)(in8 + (size_t)ep_src(p0) * ldin + f2);
            int w = c0.x | (c0.y << 8);
            x0 = __builtin_amdgcn_cvt_f32_fp8(w, 0);
            y0 = __builtin_amdgcn_cvt_f32_fp8(w, 1);
        } else {
            ushort2 v0 = *(const ushort2*)(inb + (size_t)ep_src(p0) * ldin + f2);
            x0 = b2f(v0.x);
            y0 = b2f(v0.y);
        }
        float w0 = ep_w(p0);
        a0 = fmaf(w0, x0, a0);
        a1 = fmaf(w0, y0, a1);
    }
    if (OB) {
        ushort2 o;
        o.x = f2b(a0);
        o.y = f2b(a1);
        *(ushort2*)(outb + (size_t)node * ldob + f2) = o;
    }
    if (O8) {
        int pk = __builtin_amdgcn_cvt_pk_fp8_f32(a0, a1, 0, false);
        uchar2 o8;
        o8.x = (unsigned char)(pk & 0xFF);
        o8.y = (unsigned char)((pk >> 8) & 0xFF);
        *(uchar2*)(out8 + (size_t)node * ldo8 + f2) = o8;
    }
}

// ---- width-16 fp32 propagation with addend (Horner), 16 nodes/block, 8x unroll ----
__global__ void k_prop16(const float* __restrict__ in, int ldin,
                         const float* __restrict__ add, int ldadd,
                         float* __restrict__ out, const float* __restrict__ bias,
                         const int* __restrict__ offs, const unsigned int* __restrict__ ep) {
    int node = blockIdx.x * 16 + (threadIdx.x >> 4);
    if (node >= NN) return;
    int f = threadIdx.x & 15;
    float acc = add[(size_t)node * ldadd + f];
    int s = offs[node], e = offs[node + 1];
    int t = s;
    for (; t + 8 <= e; t += 8) {
        unsigned int p[8];
        float v[8];
#pragma unroll
        for (int u = 0; u < 8; ++u) p[u] = ep[t + u];
#pragma unroll
        for (int u = 0; u < 8; ++u) v[u] = in[(size_t)ep_src(p[u]) * ldin + f];
#pragma unroll
        for (int u = 0; u < 8; ++u) acc = fmaf(ep_w(p[u]), v[u], acc);
    }
    for (; t < e; ++t) {
        unsigned int p0 = ep[t];
        acc = fmaf(ep_w(p0), in[(size_t)ep_src(p0) * ldin + f], acc);
    }
    if (bias) acc += bias[f];
    out[node * 16 + f] = acc;
}

// ---- MFMA bf16 GEMM, 128x64 tile, up to 4 A/B sources (K quarters of Kq).
// A sources bf16 (lda in elems) or fp8 e4m3 (lda in bytes) per a8mask bit.
// B bf16 TRANSPOSED: B[n][k], stride ldb.
// statsOut != nullptr: accumulate per-column sum/sumsq of the FINAL (post-relu)
// output into statsOut[c] / statsOut[512+c] (used to fuse colstats).
// cmode: 0 = write fp32, 1 = write bf16 fresh, 2 = accumulate into bf16 C ----
#define LDS_LD 40
#define SWZ(r, ko) ((ko) ^ ((((r) >> 3) & 1) << 3))
__global__ __launch_bounds__(256) void k_gemm_mfma(
    const void* __restrict__ A0, int lda0, const void* __restrict__ A1, int lda1,
    const void* __restrict__ A2, int lda2, const void* __restrict__ A3, int lda3, int a8mask,
    const u16* __restrict__ B0, const u16* __restrict__ B1, const u16* __restrict__ B2,
    const u16* __restrict__ B3, int ldb, void* __restrict__ Cv, int ldc, int M, int Ktot,
    int Kq, const float* __restrict__ bias, int relu, int cmode,
    float* __restrict__ statsOut) {
    __shared__ u16 As[128 * LDS_LD];
    __shared__ u16 Bs[64 * LDS_LD];
    __shared__ float sstat[128];  // [0..64) col sums, [64..128) col sumsq
    int tid = threadIdx.x;
    int wave = tid >> 6, lane = tid & 63;
    int quad = lane >> 4, lq = lane & 15;
    int m0 = blockIdx.y * 128, n0 = blockIdx.x * 64;
    f32x4 acc[2][4] = {};
    if (statsOut && tid < 128) sstat[tid] = 0.f;

    for (int ks = 0; ks < Ktot; ks += 32) {
        int src = ks / Kq;
        int kk = ks - src * Kq;
        const void* Ap = src == 0 ? A0 : src == 1 ? A1 : src == 2 ? A2 : A3;
        int lda = src == 0 ? lda0 : src == 1 ? lda1 : src == 2 ? lda2 : lda3;
        const u16* Bp = src == 0 ? B0 : src == 1 ? B1 : src == 2 ? B2 : B3;
        if ((a8mask >> src) & 1) {
            const unsigned char* A8 = (const unsigned char*)Ap;
#pragma unroll
            for (int i = 0; i < 2; ++i) {
                int s = tid + i * 256;
                int r = s >> 2, ko = (s & 3) << 3;
                int gr = m0 + r;
                if (gr > M - 1) gr = M - 1;
                uint2 w = *(const uint2*)(A8 + (size_t)gr * lda + kk + ko);
                // exact fp8->bf16: cvt (exact) + truncate-pack (exact on fp8 set)
                float f0 = __builtin_amdgcn_cvt_f32_fp8((int)w.x, 0);
                float f1 = __builtin_amdgcn_cvt_f32_fp8((int)w.x, 1);
                float f2_ = __builtin_amdgcn_cvt_f32_fp8((int)w.x, 2);
                float f3 = __builtin_amdgcn_cvt_f32_fp8((int)w.x, 3);
                float f4 = __builtin_amdgcn_cvt_f32_fp8((int)w.y, 0);
                float f5 = __builtin_amdgcn_cvt_f32_fp8((int)w.y, 1);
                float f6 = __builtin_amdgcn_cvt_f32_fp8((int)w.y, 2);
                float f7 = __builtin_amdgcn_cvt_f32_fp8((int)w.y, 3);
                uint4 o;
                o.x = pkhi(f0, f1);
                o.y = pkhi(f2_, f3);
                o.z = pkhi(f4, f5);
                o.w = pkhi(f6, f7);
                *(uint4*)&As[r * LDS_LD + SWZ(r, ko)] = o;
            }
        } else {
            const u16* Ab = (const u16*)Ap;
#pragma unroll
            for (int i = 0; i < 2; ++i) {
                int s = tid + i * 256;
                int r = s >> 2, ko = (s & 3) << 3;
                int gr = m0 + r;
                if (gr > M - 1) gr = M - 1;
                uint4 v = *(const uint4*)(Ab + (size_t)gr * lda + kk + ko);
                *(uint4*)&As[r * LDS_LD + SWZ(r, ko)] = v;
            }
        }
        // stage B (transposed in global): 64 n-rows x 32 k, 1 x uint4 per thread
        {
            int n = tid >> 2, ko = (tid & 3) << 3;
            uint4 v = *(const uint4*)(Bp + (size_t)(n0 + n) * ldb + kk + ko);
            *(uint4*)&Bs[n * LDS_LD + SWZ(n, ko)] = v;
        }
        __syncthreads();
        bf16x8 af[2], bfr[4];
#pragma unroll
        for (int i = 0; i < 2; ++i) {
            int r = wave * 32 + i * 16 + lq;
            af[i] = *(bf16x8*)&As[r * LDS_LD + SWZ(r, quad * 8)];
        }
#pragma unroll
        for (int j = 0; j < 4; ++j) {
            int r = j * 16 + lq;
            bfr[j] = *(bf16x8*)&Bs[r * LDS_LD + SWZ(r, quad * 8)];
        }
#pragma unroll
        for (int i = 0; i < 2; ++i)
#pragma unroll
            for (int j = 0; j < 4; ++j)
                acc[i][j] = __builtin_amdgcn_mfma_f32_16x16x32_bf16(af[i], bfr[j], acc[i][j],
                                                                    0, 0, 0);
        __syncthreads();
    }
#pragma unroll
    for (int i = 0; i < 2; ++i) {
#pragma unroll
        for (int j = 0; j < 4; ++j) {
            int c = n0 + j * 16 + lq;
            float bcol = bias ? bias[c] : 0.f;
            int rbase = m0 + wave * 32 + i * 16 + quad * 4;
            float ls = 0.f, lq2 = 0.f;
#pragma unroll
            for (int reg = 0; reg < 4; ++reg) {
                int r = rbase + reg;
                if (r >= M) continue;
                float t = acc[i][j][reg];
                if (cmode == 2) t += b2f(*((u16*)Cv + (size_t)r * ldc + c));
                t += bcol;
                if (relu) t = fmaxf(t, 0.f);
                if (cmode == 0)
                    ((float*)Cv)[(size_t)r * ldc + c] = t;
                else
                    *((u16*)Cv + (size_t)r * ldc + c) = f2b(t);
                ls += t;
                lq2 += t * t;
            }
            if (statsOut) {
                int jc = j * 16 + lq;
                atomicAdd(&sstat[jc], ls);
                atomicAdd(&sstat[64 + jc], lq2);
            }
        }
    }
    if (statsOut) {
        __syncthreads();
        if (tid < 64) atomicAdd(&statsOut[n0 + tid], sstat[tid]);
        else if (tid < 128) atomicAdd(&statsOut[512 + n0 + (tid - 64)], sstat[tid]);
    }
}

// ---------------- graphnorm apply (in place, bf16) ----------------
__global__ void k_gnorm(u16* __restrict__ X, int ld, const float* __restrict__ stats,
                        const float* __restrict__ w, const float* __restrict__ b,
                        const float* __restrict__ a) {
    int i = blockIdx.x;
    int c = threadIdx.x * 2;
    const float invn = 1.f / NN;
    ushort2 v = *(ushort2*)(X + (size_t)i * ld + c);
    float x0 = b2f(v.x), x1 = b2f(v.y);
    {
        float m = stats[c] * invn, q = stats[512 + c] * invn, al = a[c];
        float var = q - (2.f * al - al * al) * m * m;
        x0 = (x0 - al * m) * rsqrtf(var + EPSF) * w[c] + b[c];
    }
    {
        int c1 = c + 1;
        float m = stats[c1] * invn, q = stats[512 + c1] * invn, al = a[c1];
        float var = q - (2.f * al - al * al) * m * m;
        x1 = (x1 - al * m) * rsqrtf(var + EPSF) * w[c1] + b[c1];
    }
    v.x = f2b(x0);
    v.y = f2b(x1);
    *(ushort2*)(X + (size_t)i * ld + c) = v;
}

// ---- transpose weights: src (KH, I, O) fp32 -> dst (KH, O, I) bf16 ----
__global__ void k_wt(const float* __restrict__ src, u16* __restrict__ dst, int I, int O,
                     int total) {
    int idx = blockIdx.x * 256 + threadIdx.x;
    if (idx >= total) return;
    int io = I * O;
    int k = idx / io, rem = idx - k * io;
    int n = rem / I, i = rem - n * I;
    dst[idx] = f2b(src[(size_t)k * io + (size_t)i * O + n]);
}

// ---- W3 (4,512,16) fp32 -> W3T (64, 512) bf16 : W3T[k*16+f][i] = W3[k][i][f] ----
__global__ void k_wt3(const float* __restrict__ W3, u16* __restrict__ W3T) {
    int idx = blockIdx.x * 256 + threadIdx.x;
    if (idx >= 64 * 512) return;
    int n = idx >> 9, i = idx & 511;
    int k = n >> 4, f = n & 15;
    W3T[idx] = f2b(W3[((size_t)k * 512 + i) * 16 + f]);
}

extern "C" void kernel_launch(void* const* d_in, const int* in_sizes, int n_in,
                              void* d_out, int out_size, void* d_ws, size_t ws_size,
                              hipStream_t stream) {
    const float* x = (const float*)d_in[0];
    const int* ei = (const int*)d_in[1];
    const float* W1 = (const float*)d_in[2];
    const float* b1 = (const float*)d_in[3];
    const float* W2 = (const float*)d_in[4];
    const float* b2 = (const float*)d_in[5];
    const float* W3 = (const float*)d_in[6];
    const float* b3 = (const float*)d_in[7];
    const float* g1w = (const float*)d_in[8];
    const float* g1b = (const float*)d_in[9];
    const float* g1a = (const float*)d_in[10];
    const float* g2w = (const float*)d_in[11];
    const float* g2b = (const float*)d_in[12];
    const float* g2a = (const float*)d_in[13];
    const int* row = ei;
    const int* col = ei + EE;

    char* p = (char*)d_ws;
    auto alloc = [&](size_t bytes) {
        char* r = p;
        p += (bytes + 255) & ~(size_t)255;
        return r;
    };
    // Total workspace ~247.5 MB (rounds 8-12 proven budget)
    u16* H1 = (u16*)alloc((size_t)NN * 512 * 2);                  // 102.4 MB
    u16* Y = (u16*)alloc((size_t)NN * 512 * 2);                   // 102.4 MB
    unsigned char* XF = (unsigned char*)alloc((size_t)NN * 256);  // 25.6 MB: F8a|F8b
    unsigned int* ep = (unsigned int*)alloc((size_t)EE * 4);      // 12.8 MB
    u16* W1T = (u16*)alloc((size_t)4 * 512 * 128 * 2);            // 0.5 MB
    u16* W2T = (u16*)alloc((size_t)4 * 512 * 512 * 2);            // 2.0 MB
    u16* W3T = (u16*)alloc(64 * 512 * 2);                         // 64 KB
    float* dinv = (float*)alloc((size_t)NN * 4);
    float* stats = (float*)alloc(2048 * 4);
    int* deg = (int*)alloc((size_t)NN * 4);
    int* offs = (int*)alloc((size_t)(NN + 1) * 4);
    int* cursor = (int*)alloc((size_t)NN * 4);
    (void)ws_size;
    (void)in_sizes;
    (void)n_in;
    (void)out_size;

    unsigned char* F8a = XF;
    unsigned char* F8b = XF + (size_t)NN * 128;
    u16* xb = Y;  // N x 128 bf16 (ld 128) parked in Y; dead before L2 GEMM1 writes Y

    // ---- CSR build + weight transpose/convert
    k_init<<<cdiv(NN, 256), 256, 0, stream>>>(deg, cursor, stats);
    k_deg<<<cdiv(EE, 256), 256, 0, stream>>>(col, deg);
    k_dinv<<<cdiv(NN, 256), 256, 0, stream>>>(deg, dinv);
    k_scan<<<1, 1024, 0, stream>>>(deg, offs);
    k_scatter<<<cdiv(EE, 256), 256, 0, stream>>>(row, col, dinv, offs, cursor, ep);
    k_wt<<<cdiv(4 * 128 * 512, 256), 256, 0, stream>>>(W1, W1T, 128, 512, 4 * 128 * 512);
    k_wt<<<cdiv(4 * 512 * 512, 256), 256, 0, stream>>>(W2, W2T, 512, 512, 4 * 512 * 512);
    k_wt3<<<cdiv(64 * 512, 256), 256, 0, stream>>>(W3, W3T);

    dim3 gg(512 / 64, cdiv(NN, 128));  // (8, 782), 128x64 tiles
    const size_t WQ = (size_t)512 * 512;   // per-hop stride in W2T
    const size_t W1Q = (size_t)512 * 128;  // per-hop stride in W1T

    // ---- layer 1: H1 = sum_k (A^k x) W1[k]; hops 2,3 fp8 end-to-end;
    //      colstats fused into GEMM2 epilogue
    k_cvt<<<cdiv(NN * 32, 256), 256, 0, stream>>>(x, xb, NN * 32);
    k_prop_t<0, 0, 1><<<NN, 64, 0, stream>>>(xb, 128, nullptr, 0, F8a, 128, offs, ep);
    k_gemm_mfma<<<gg, 256, 0, stream>>>(xb, 128, F8a, 128, xb, 128, xb, 128, 2, W1T,
                                        W1T + W1Q, W1T, W1T, 128, H1, 512, NN, 256, 128,
                                        nullptr, 0, 1, nullptr);
    k_prop_t<1, 0, 1><<<NN, 64, 0, stream>>>(F8a, 128, nullptr, 0, F8b, 128, offs, ep);
    k_prop_t<1, 0, 1><<<NN, 64, 0, stream>>>(F8b, 128, nullptr, 0, F8a, 128, offs, ep);
    k_gemm_mfma<<<gg, 256, 0, stream>>>(F8b, 128, F8a, 128, xb, 128, xb, 128, 3,
                                        W1T + 2 * W1Q, W1T + 3 * W1Q, W1T, W1T, 128, H1, 512,
                                        NN, 256, 128, b1, 1, 2, stats);
    k_gnorm<<<NN, 256, 0, stream>>>(H1, 512, stats, g1w, g1b, g1a);

    // ---- layer 2: Y = sum_k (A^k h1) W2[k], K-chunked by 128. Hops fp8 end-to-end.
    // Chunks 0,1: 2-GEMM split (no dead slices yet).
    for (int c = 0; c < 2; ++c) {
        u16* h1c = H1 + 128 * c;        // ld 512
        const u16* Wc = W2T + 128 * c;  // in-offset within transposed rows
        k_prop_t<0, 0, 1><<<NN, 64, 0, stream>>>(h1c, 512, nullptr, 0, F8a, 128, offs, ep);
        k_gemm_mfma<<<gg, 256, 0, stream>>>(h1c, 512, F8a, 128, h1c, 512, h1c, 512, 2, Wc,
                                            Wc + WQ, Wc, Wc, 512, Y, 512, NN, 256, 128,
                                            nullptr, 0, c == 0 ? 1 : 2, nullptr);
        k_prop_t<1, 0, 1><<<NN, 64, 0, stream>>>(F8a, 128, nullptr, 0, F8b, 128, offs, ep);
        k_prop_t<1, 0, 1><<<NN, 64, 0, stream>>>(F8b, 128, nullptr, 0, F8a, 128, offs, ep);
        k_gemm_mfma<<<gg, 256, 0, stream>>>(F8b, 128, F8a, 128, h1c, 512, h1c, 512, 3,
                                            Wc + 2 * WQ, Wc + 3 * WQ, Wc, Wc, 512, Y, 512, NN,
                                            256, 128, nullptr, 0, 2, nullptr);
    }
    // Chunks 2,3: hop3 parked fp8 in dead H1 slice 0 -> ONE K=512 GEMM each.
    // Final (c==3) GEMM also emits col stats (fused colstats).
    for (int c = 2; c < 4; ++c) {
        u16* h1c = H1 + 128 * c;                  // ld 512, alive
        unsigned char* F8c = (unsigned char*)H1;  // dead slice 0, fp8 ld 1024 B
        const u16* Wc = W2T + 128 * c;
        k_prop_t<0, 0, 1><<<NN, 64, 0, stream>>>(h1c, 512, nullptr, 0, F8a, 128, offs, ep);
        k_prop_t<1, 0, 1><<<NN, 64, 0, stream>>>(F8a, 128, nullptr, 0, F8b, 128, offs, ep);
        k_prop_t<1, 0, 1><<<NN, 64, 0, stream>>>(F8b, 128, nullptr, 0, F8c, 1024, offs, ep);
        k_gemm_mfma<<<gg, 256, 0, stream>>>(h1c, 512, F8a, 128, F8b, 128, F8c, 1024, 14, Wc,
                                            Wc + WQ, Wc + 2 * WQ, Wc + 3 * WQ, 512, Y, 512, NN,
                                            512, 128, (c == 3) ? b2 : nullptr, c == 3 ? 1 : 0,
                                            2, (c == 3) ? (stats + 1024) : nullptr);
    }
    k_gnorm<<<NN, 256, 0, stream>>>(Y, 512, stats + 1024, g2w, g2b, g2a);

    // ---- layer 3 (Horner at width 16): G = h2 @ [W3_0|W3_1|W3_2|W3_3] (fp32, in H1 space)
    float* G = (float*)H1;             // N x 64 fp32 = 25.6 MB
    float* tA = (float*)XF;            // N x 16 fp32 = 6.4 MB
    float* tB = tA + (size_t)NN * 16;  // 6.4 MB (XF holds both)
    {
        dim3 g3(1, cdiv(NN, 128));
        k_gemm_mfma<<<g3, 256, 0, stream>>>(Y, 512, Y, 512, Y, 512, Y, 512, 0, W3T, W3T, W3T,
                                            W3T, 512, G, 64, NN, 512, 512, nullptr, 0, 0,
                                            nullptr);
    }
    k_prop16<<<cdiv(NN, 16), 256, 0, stream>>>(G + 48, 64, G + 32, 64, tA, nullptr, offs, ep);
    k_prop16<<<cdiv(NN, 16), 256, 0, stream>>>(tA, 16, G + 16, 64, tB, nullptr, offs, ep);
    k_prop16<<<cdiv(NN, 16), 256, 0, stream>>>(tB, 16, G + 0, 64, (float*)d_out, b3, offs, ep);
}

// Round 15
// 2795.269 us; speedup vs baseline: 1.3204x; 1.1551x over previous
//
#include <hip/hip_runtime.h>

#define NN 100000
#define EE 3200000
#define EPSF 1e-5f

typedef unsigned short u16;
typedef short bf16x8 __attribute__((ext_vector_type(8)));
typedef float f32x4 __attribute__((ext_vector_type(4)));

static inline int cdiv(int a, int b) { return (a + b - 1) / b; }

__device__ __forceinline__ float b2f(u16 u) {
    return __uint_as_float((unsigned int)u << 16);
}
__device__ __forceinline__ u16 f2b(float f) {
    unsigned int i = __float_as_uint(f);
    return (u16)((i + 0x7FFFu + ((i >> 16) & 1u)) >> 16);  // RNE
}
// packed edge: [31:17] = positive float top bits, [16:0] = src index
__device__ __forceinline__ int ep_src(unsigned int p) { return (int)(p & 0x1FFFFu); }
__device__ __forceinline__ float ep_w(unsigned int p) {
    return __uint_as_float(p & 0xFFFE0000u);
}
// pack high16(f0) | high16(f1)<<16 — exact bf16 for values exactly representable (fp8 set)
__device__ __forceinline__ unsigned pkhi(float f0, float f1) {
    return __builtin_amdgcn_perm(__float_as_uint(f1), __float_as_uint(f0), 0x07060302u);
}

// ---------------- zero-init (graph-capture-safe) ----------------
__global__ void k_init(int* __restrict__ deg, int* __restrict__ cursor,
                       float* __restrict__ stats) {
    int i = blockIdx.x * 256 + threadIdx.x;
    if (i < NN) {
        deg[i] = 0;
        cursor[i] = 0;
    }
    if (i < 2048) stats[i] = 0.f;
}

// ---------------- degree histogram ----------------
__global__ void k_deg(const int* __restrict__ col, int* __restrict__ deg) {
    int i = blockIdx.x * 256 + threadIdx.x;
    if (i < EE) atomicAdd(&deg[col[i]], 1);
}

__global__ void k_dinv(const int* __restrict__ deg, float* __restrict__ dinv) {
    int i = blockIdx.x * 256 + threadIdx.x;
    if (i < NN) {
        int d = deg[i];
        dinv[i] = d > 0 ? rsqrtf((float)d) : 0.f;
    }
}

// ------- exclusive scan: 1024 threads, 98 contiguous elems per thread -------
__global__ void k_scan(const int* __restrict__ deg, int* __restrict__ offs) {
    __shared__ int sh[1024];
    int tid = threadIdx.x;
    int start = tid * 98;
    int end = min(start + 98, NN);
    int sum = 0;
    for (int i = start; i < end; ++i) sum += deg[i];
    sh[tid] = sum;
    __syncthreads();
    for (int off = 1; off < 1024; off <<= 1) {
        int t = (tid >= off) ? sh[tid - off] : 0;
        __syncthreads();
        sh[tid] += t;
        __syncthreads();
    }
    int base = tid ? sh[tid - 1] : 0;
    for (int i = start; i < end; ++i) {
        offs[i] = base;
        base += deg[i];
    }
    if (tid == 1023) offs[NN] = sh[1023];
}

// ---------------- CSR scatter: pack (w:15 | src:17) into one u32 ----------------
__global__ void k_scatter(const int* __restrict__ row, const int* __restrict__ col,
                          const float* __restrict__ dinv, const int* __restrict__ offs,
                          int* __restrict__ cursor, unsigned int* __restrict__ ep) {
    int i = blockIdx.x * 256 + threadIdx.x;
    if (i < EE) {
        int c = col[i], r = row[i];
        int pos = offs[c] + atomicAdd(&cursor[c], 1);
        float w = dinv[r] * dinv[c];  // >= 0
        unsigned int u = __float_as_uint(w);
        unsigned int rb = (u + 0xFFFFu + ((u >> 17) & 1u)) & 0xFFFE0000u;  // RNE @ 7-bit man
        ep[pos] = rb | (unsigned int)r;
    }
}

// ---------------- convert fp32 array -> bf16 (n4 = count of float4s) ----------------
__global__ void k_cvt(const float* __restrict__ src, u16* __restrict__ dst, int n4) {
    int idx = blockIdx.x * 256 + threadIdx.x;
    if (idx >= n4) return;
    float4 v = ((const float4*)src)[idx];
    ushort4 o;
    o.x = f2b(v.x);
    o.y = f2b(v.y);
    o.z = f2b(v.z);
    o.w = f2b(v.w);
    ((ushort4*)dst)[idx] = o;
}

// ---- convert a width-256 bf16 slice (lds_ elems) -> fp8 (ldd bytes), sequential ----
__global__ void k_cvt8s(const u16* __restrict__ src, int lds_, unsigned char* __restrict__ dst,
                        int ldd) {
    int idx = blockIdx.x * 256 + threadIdx.x;  // over NN*128 (2 elems each)
    if (idx >= NN * 128) return;
    int node = idx >> 7, f2 = (idx & 127) << 1;
    ushort2 v = *(const ushort2*)(src + (size_t)node * lds_ + f2);
    int pk = __builtin_amdgcn_cvt_pk_fp8_f32(b2f(v.x), b2f(v.y), 0, false);
    uchar2 o;
    o.x = (unsigned char)(pk & 0xFF);
    o.y = (unsigned char)((pk >> 8) & 0xFF);
    *(uchar2*)(dst + (size_t)node * ldd + f2) = o;
}

// ---- gather propagation, width 128, 64 thr/node, 4x unroll (layer 1), fp8 out.
// S8: source fp8 (ldin in bytes) else bf16 (ldin in elems). ----
template <int S8>
__global__ void k_prop_t(const void* __restrict__ in, int ldin,
                         unsigned char* __restrict__ out8, int ldo8,
                         const int* __restrict__ offs, const unsigned int* __restrict__ ep) {
    int node = blockIdx.x;
    int f2 = threadIdx.x << 1;
    int s = offs[node], e = offs[node + 1];
    const u16* inb = (const u16*)in;
    const unsigned char* in8 = (const unsigned char*)in;
    float a0 = 0.f, a1 = 0.f;
    int t = s;
    for (; t + 4 <= e; t += 4) {
        unsigned int p0 = ep[t], p1 = ep[t + 1], p2 = ep[t + 2], p3 = ep[t + 3];
        float x0, y0, x1, y1, x2, y2, x3, y3;
        if (S8) {
            uchar2 c0 = *(const uchar2*)(in8 + (size_t)ep_src(p0) * ldin + f2);
            uchar2 c1 = *(const uchar2*)(in8 + (size_t)ep_src(p1) * ldin + f2);
            uchar2 c2 = *(const uchar2*)(in8 + (size_t)ep_src(p2) * ldin + f2);
            uchar2 c3 = *(const uchar2*)(in8 + (size_t)ep_src(p3) * ldin + f2);
            int w0 = c0.x | (c0.y << 8), w1 = c1.x | (c1.y << 8);
            int w2 = c2.x | (c2.y << 8), w3 = c3.x | (c3.y << 8);
            x0 = __builtin_amdgcn_cvt_f32_fp8(w0, 0);
            y0 = __builtin_amdgcn_cvt_f32_fp8(w0, 1);
            x1 = __builtin_amdgcn_cvt_f32_fp8(w1, 0);
            y1 = __builtin_amdgcn_cvt_f32_fp8(w1, 1);
            x2 = __builtin_amdgcn_cvt_f32_fp8(w2, 0);
            y2 = __builtin_amdgcn_cvt_f32_fp8(w2, 1);
            x3 = __builtin_amdgcn_cvt_f32_fp8(w3, 0);
            y3 = __builtin_amdgcn_cvt_f32_fp8(w3, 1);
        } else {
            ushort2 v0 = *(const ushort2*)(inb + (size_t)ep_src(p0) * ldin + f2);
            ushort2 v1 = *(const ushort2*)(inb + (size_t)ep_src(p1) * ldin + f2);
            ushort2 v2 = *(const ushort2*)(inb + (size_t)ep_src(p2) * ldin + f2);
            ushort2 v3 = *(const ushort2*)(inb + (size_t)ep_src(p3) * ldin + f2);
            x0 = b2f(v0.x);
            y0 = b2f(v0.y);
            x1 = b2f(v1.x);
            y1 = b2f(v1.y);
            x2 = b2f(v2.x);
            y2 = b2f(v2.y);
            x3 = b2f(v3.x);
            y3 = b2f(v3.y);
        }
        float w0 = ep_w(p0), w1 = ep_w(p1), w2 = ep_w(p2), w3 = ep_w(p3);
        a0 = fmaf(w0, x0, a0);
        a1 = fmaf(w0, y0, a1);
        a0 = fmaf(w1, x1, a0);
        a1 = fmaf(w1, y1, a1);
        a0 = fmaf(w2, x2, a0);
        a1 = fmaf(w2, y2, a1);
        a0 = fmaf(w3, x3, a0);
        a1 = fmaf(w3, y3, a1);
    }
    for (; t < e; ++t) {
        unsigned int p0 = ep[t];
        float x0, y0;
        if (S8) {
            uchar2 c0 = *(const uchar2*)(in8 + (size_t)ep_src(p0) * ldin + f2);
            int w = c0.x | (c0.y << 8);
            x0 = __builtin_amdgcn_cvt_f32_fp8(w, 0);
            y0 = __builtin_amdgcn_cvt_f32_fp8(w, 1);
        } else {
            ushort2 v0 = *(const ushort2*)(inb + (size_t)ep_src(p0) * ldin + f2);
            x0 = b2f(v0.x);
            y0 = b2f(v0.y);
        }
        float w0 = ep_w(p0);
        a0 = fmaf(w0, x0, a0);
        a1 = fmaf(w0, y0, a1);
    }
    int pk = __builtin_amdgcn_cvt_pk_fp8_f32(a0, a1, 0, false);
    uchar2 o8;
    o8.x = (unsigned char)(pk & 0xFF);
    o8.y = (unsigned char)((pk >> 8) & 0xFF);
    *(uchar2*)(out8 + (size_t)node * ldo8 + f2) = o8;
}

// ---- width-256 fp8 propagation: one wave/node, 4 cols/lane (one dword gather/edge) ----
__global__ void k_prop256(const unsigned char* __restrict__ in, int ldin,
                          unsigned char* __restrict__ out, int ldout,
                          const int* __restrict__ offs, const unsigned int* __restrict__ ep) {
    int node = blockIdx.x;
    int f4 = threadIdx.x << 2;
    int s = offs[node], e = offs[node + 1];
    float a0 = 0, a1 = 0, a2 = 0, a3 = 0;
    int t = s;
    for (; t + 4 <= e; t += 4) {
        unsigned int p[4];
        unsigned int v[4];
#pragma unroll
        for (int u = 0; u < 4; ++u) p[u] = ep[t + u];
#pragma unroll
        for (int u = 0; u < 4; ++u)
            v[u] = *(const unsigned int*)(in + (size_t)ep_src(p[u]) * ldin + f4);
#pragma unroll
        for (int u = 0; u < 4; ++u) {
            float w = ep_w(p[u]);
            a0 = fmaf(w, __builtin_amdgcn_cvt_f32_fp8((int)v[u], 0), a0);
            a1 = fmaf(w, __builtin_amdgcn_cvt_f32_fp8((int)v[u], 1), a1);
            a2 = fmaf(w, __builtin_amdgcn_cvt_f32_fp8((int)v[u], 2), a2);
            a3 = fmaf(w, __builtin_amdgcn_cvt_f32_fp8((int)v[u], 3), a3);
        }
    }
    for (; t < e; ++t) {
        unsigned int p0 = ep[t];
        unsigned int v = *(const unsigned int*)(in + (size_t)ep_src(p0) * ldin + f4);
        float w = ep_w(p0);
        a0 = fmaf(w, __builtin_amdgcn_cvt_f32_fp8((int)v, 0), a0);
        a1 = fmaf(w, __builtin_amdgcn_cvt_f32_fp8((int)v, 1), a1);
        a2 = fmaf(w, __builtin_amdgcn_cvt_f32_fp8((int)v, 2), a2);
        a3 = fmaf(w, __builtin_amdgcn_cvt_f32_fp8((int)v, 3), a3);
    }
    int p01 = __builtin_amdgcn_cvt_pk_fp8_f32(a0, a1, 0, false);
    int p23 = __builtin_amdgcn_cvt_pk_fp8_f32(a2, a3, 0, false);
    unsigned int o = (unsigned)(p01 & 0xFFFF) | ((unsigned)p23 << 16);
    *(unsigned int*)(out + (size_t)node * ldout + f4) = o;
}

// ---- width-16 fp32 propagation with addend (Horner), 16 nodes/block, 8x unroll ----
__global__ void k_prop16(const float* __restrict__ in, int ldin,
                         const float* __restrict__ add, int ldadd,
                         float* __restrict__ out, const float* __restrict__ bias,
                         const int* __restrict__ offs, const unsigned int* __restrict__ ep) {
    int node = blockIdx.x * 16 + (threadIdx.x >> 4);
    if (node >= NN) return;
    int f = threadIdx.x & 15;
    float acc = add[(size_t)node * ldadd + f];
    int s = offs[node], e = offs[node + 1];
    int t = s;
    for (; t + 8 <= e; t += 8) {
        unsigned int p[8];
        float v[8];
#pragma unroll
        for (int u = 0; u < 8; ++u) p[u] = ep[t + u];
#pragma unroll
        for (int u = 0; u < 8; ++u) v[u] = in[(size_t)ep_src(p[u]) * ldin + f];
#pragma unroll
        for (int u = 0; u < 8; ++u) acc = fmaf(ep_w(p[u]), v[u], acc);
    }
    for (; t < e; ++t) {
        unsigned int p0 = ep[t];
        acc = fmaf(ep_w(p0), in[(size_t)ep_src(p0) * ldin + f], acc);
    }
    if (bias) acc += bias[f];
    out[node * 16 + f] = acc;
}

// ---- MFMA bf16 GEMM, 128x64 tile, up to 4 A/B sources (K quarters of Kq).
// A sources bf16 (lda in elems) or fp8 e4m3 (lda in bytes) per a8mask bit.
// B bf16 TRANSPOSED: B[n][k], stride ldb.
// statsOut: fuse per-column sum/sumsq of final output. ----
#define LDS_LD 40
#define SWZ(r, ko) ((ko) ^ ((((r) >> 3) & 1) << 3))
__global__ __launch_bounds__(256) void k_gemm_mfma(
    const void* __restrict__ A0, int lda0, const void* __restrict__ A1, int lda1,
    const void* __restrict__ A2, int lda2, const void* __restrict__ A3, int lda3, int a8mask,
    const u16* __restrict__ B0, const u16* __restrict__ B1, const u16* __restrict__ B2,
    const u16* __restrict__ B3, int ldb, void* __restrict__ Cv, int ldc, int M, int Ktot,
    int Kq, const float* __restrict__ bias, int relu, int cmode,
    float* __restrict__ statsOut) {
    __shared__ u16 As[128 * LDS_LD];
    __shared__ u16 Bs[64 * LDS_LD];
    __shared__ float sstat[128];
    int tid = threadIdx.x;
    int wave = tid >> 6, lane = tid & 63;
    int quad = lane >> 4, lq = lane & 15;
    int m0 = blockIdx.y * 128, n0 = blockIdx.x * 64;
    f32x4 acc[2][4] = {};
    if (statsOut && tid < 128) sstat[tid] = 0.f;

    for (int ks = 0; ks < Ktot; ks += 32) {
        int src = ks / Kq;
        int kk = ks - src * Kq;
        const void* Ap = src == 0 ? A0 : src == 1 ? A1 : src == 2 ? A2 : A3;
        int lda = src == 0 ? lda0 : src == 1 ? lda1 : src == 2 ? lda2 : lda3;
        const u16* Bp = src == 0 ? B0 : src == 1 ? B1 : src == 2 ? B2 : B3;
        if ((a8mask >> src) & 1) {
            const unsigned char* A8 = (const unsigned char*)Ap;
#pragma unroll
            for (int i = 0; i < 2; ++i) {
                int s = tid + i * 256;
                int r = s >> 2, ko = (s & 3) << 3;
                int gr = m0 + r;
                if (gr > M - 1) gr = M - 1;
                uint2 w = *(const uint2*)(A8 + (size_t)gr * lda + kk + ko);
                float f0 = __builtin_amdgcn_cvt_f32_fp8((int)w.x, 0);
                float f1 = __builtin_amdgcn_cvt_f32_fp8((int)w.x, 1);
                float f2_ = __builtin_amdgcn_cvt_f32_fp8((int)w.x, 2);
                float f3 = __builtin_amdgcn_cvt_f32_fp8((int)w.x, 3);
                float f4 = __builtin_amdgcn_cvt_f32_fp8((int)w.y, 0);
                float f5 = __builtin_amdgcn_cvt_f32_fp8((int)w.y, 1);
                float f6 = __builtin_amdgcn_cvt_f32_fp8((int)w.y, 2);
                float f7 = __builtin_amdgcn_cvt_f32_fp8((int)w.y, 3);
                uint4 o;
                o.x = pkhi(f0, f1);
                o.y = pkhi(f2_, f3);
                o.z = pkhi(f4, f5);
                o.w = pkhi(f6, f7);
                *(uint4*)&As[r * LDS_LD + SWZ(r, ko)] = o;
            }
        } else {
            const u16* Ab = (const u16*)Ap;
#pragma unroll
            for (int i = 0; i < 2; ++i) {
                int s = tid + i * 256;
                int r = s >> 2, ko = (s & 3) << 3;
                int gr = m0 + r;
                if (gr > M - 1) gr = M - 1;
                uint4 v = *(const uint4*)(Ab + (size_t)gr * lda + kk + ko);
                *(uint4*)&As[r * LDS_LD + SWZ(r, ko)] = v;
            }
        }
        {
            int n = tid >> 2, ko = (tid & 3) << 3;
            uint4 v = *(const uint4*)(Bp + (size_t)(n0 + n) * ldb + kk + ko);
            *(uint4*)&Bs[n * LDS_LD + SWZ(n, ko)] = v;
        }
        __syncthreads();
        bf16x8 af[2], bfr[4];
#pragma unroll
        for (int i = 0; i < 2; ++i) {
            int r = wave * 32 + i * 16 + lq;
            af[i] = *(bf16x8*)&As[r * LDS_LD + SWZ(r, quad * 8)];
        }
#pragma unroll
        for (int j = 0; j < 4; ++j) {
            int r = j * 16 + lq;
            bfr[j] = *(bf16x8*)&Bs[r * LDS_LD + SWZ(r, quad * 8)];
        }
#pragma unroll
        for (int i = 0; i < 2; ++i)
#pragma unroll
            for (int j = 0; j < 4; ++j)
                acc[i][j] = __builtin_amdgcn_mfma_f32_16x16x32_bf16(af[i], bfr[j], acc[i][j],
                                                                    0, 0, 0);
        __syncthreads();
    }
#pragma unroll
    for (int i = 0; i < 2; ++i) {
#pragma unroll
        for (int j = 0; j < 4; ++j) {
            int c = n0 + j * 16 + lq;
            float bcol = bias ? bias[c] : 0.f;
            int rbase = m0 + wave * 32 + i * 16 + quad * 4;
            float ls = 0.f, lq2 = 0.f;
#pragma unroll
            for (int reg = 0; reg < 4; ++reg) {
                int r = rbase + reg;
                if (r >= M) continue;
                float t = acc[i][j][reg];
                if (cmode == 2) t += b2f(*((u16*)Cv + (size_t)r * ldc + c));
                t += bcol;
                if (relu) t = fmaxf(t, 0.f);
                if (cmode == 0)
                    ((float*)Cv)[(size_t)r * ldc + c] = t;
                else
                    *((u16*)Cv + (size_t)r * ldc + c) = f2b(t);
                ls += t;
                lq2 += t * t;
            }
            if (statsOut) {
                int jc = j * 16 + lq;
                atomicAdd(&sstat[jc], ls);
                atomicAdd(&sstat[64 + jc], lq2);
            }
        }
    }
    if (statsOut) {
        __syncthreads();
        if (tid < 64) atomicAdd(&statsOut[n0 + tid], sstat[tid]);
        else if (tid < 128) atomicAdd(&statsOut[512 + n0 + (tid - 64)], sstat[tid]);
    }
}

// ---------------- graphnorm apply (in place, bf16) ----------------
__global__ void k_gnorm(u16* __restrict__ X, int ld, const float* __restrict__ stats,
                        const float* __restrict__ w, const float* __restrict__ b,
                        const float* __restrict__ a) {
    int i = blockIdx.x;
    int c = threadIdx.x * 2;
    const float invn = 1.f / NN;
    ushort2 v = *(ushort2*)(X + (size_t)i * ld + c);
    float x0 = b2f(v.x), x1 = b2f(v.y);
    {
        float m = stats[c] * invn, q = stats[512 + c] * invn, al = a[c];
        float var = q - (2.f * al - al * al) * m * m;
        x0 = (x0 - al * m) * rsqrtf(var + EPSF) * w[c] + b[c];
    }
    {
        int c1 = c + 1;
        float m = stats[c1] * invn, q = stats[512 + c1] * invn, al = a[c1];
        float var = q - (2.f * al - al * al) * m * m;
        x1 = (x1 - al * m) * rsqrtf(var + EPSF) * w[c1] + b[c1];
    }
    v.x = f2b(x0);
    v.y = f2b(x1);
    *(ushort2*)(X + (size_t)i * ld + c) = v;
}

// ---- transpose weights: src (KH, I, O) fp32 -> dst (KH, O, I) bf16 ----
__global__ void k_wt(const float* __restrict__ src, u16* __restrict__ dst, int I, int O,
                     int total) {
    int idx = blockIdx.x * 256 + threadIdx.x;
    if (idx >= total) return;
    int io = I * O;
    int k = idx / io, rem = idx - k * io;
    int n = rem / I, i = rem - n * I;
    dst[idx] = f2b(src[(size_t)k * io + (size_t)i * O + n]);
}

// ---- W3 (4,512,16) fp32 -> W3T (64, 512) bf16 : W3T[k*16+f][i] = W3[k][i][f] ----
__global__ void k_wt3(const float* __restrict__ W3, u16* __restrict__ W3T) {
    int idx = blockIdx.x * 256 + threadIdx.x;
    if (idx >= 64 * 512) return;
    int n = idx >> 9, i = idx & 511;
    int k = n >> 4, f = n & 15;
    W3T[idx] = f2b(W3[((size_t)k * 512 + i) * 16 + f]);
}

extern "C" void kernel_launch(void* const* d_in, const int* in_sizes, int n_in,
                              void* d_out, int out_size, void* d_ws, size_t ws_size,
                              hipStream_t stream) {
    const float* x = (const float*)d_in[0];
    const int* ei = (const int*)d_in[1];
    const float* W1 = (const float*)d_in[2];
    const float* b1 = (const float*)d_in[3];
    const float* W2 = (const float*)d_in[4];
    const float* b2 = (const float*)d_in[5];
    const float* W3 = (const float*)d_in[6];
    const float* b3 = (const float*)d_in[7];
    const float* g1w = (const float*)d_in[8];
    const float* g1b = (const float*)d_in[9];
    const float* g1a = (const float*)d_in[10];
    const float* g2w = (const float*)d_in[11];
    const float* g2b = (const float*)d_in[12];
    const float* g2a = (const float*)d_in[13];
    const int* row = ei;
    const int* col = ei + EE;

    char* p = (char*)d_ws;
    auto alloc = [&](size_t bytes) {
        char* r = p;
        p += (bytes + 255) & ~(size_t)255;
        return r;
    };
    // Total workspace ~247.5 MB (rounds 8-13 proven budget)
    u16* H1 = (u16*)alloc((size_t)NN * 512 * 2);                  // 102.4 MB: h1 / hop fp8 park
    u16* Y = (u16*)alloc((size_t)NN * 512 * 2);                   // 102.4 MB: L1 scratch -> Y
    unsigned char* X8 = (unsigned char*)alloc((size_t)NN * 256);  // 25.6 MB fp8 width-256
    unsigned int* ep = (unsigned int*)alloc((size_t)EE * 4);      // 12.8 MB
    u16* W1T = (u16*)alloc((size_t)4 * 512 * 128 * 2);            // 0.5 MB
    u16* W2T = (u16*)alloc((size_t)4 * 512 * 512 * 2);            // 2.0 MB
    u16* W3T = (u16*)alloc(64 * 512 * 2);                         // 64 KB
    float* dinv = (float*)alloc((size_t)NN * 4);
    float* stats = (float*)alloc(2048 * 4);
    int* deg = (int*)alloc((size_t)NN * 4);
    int* offs = (int*)alloc((size_t)(NN + 1) * 4);
    int* cursor = (int*)alloc((size_t)NN * 4);
    (void)ws_size;
    (void)in_sizes;
    (void)n_in;
    (void)out_size;

    // L1 scratch parked in Y (dead before L2 GEMM1 writes Y):
    u16* xb = Y;                                           // N x 128 bf16 (25.6 MB)
    unsigned char* F8a = (unsigned char*)Y + (size_t)NN * 256;        // N x 128 fp8
    unsigned char* F8b = (unsigned char*)Y + (size_t)NN * 256 + (size_t)NN * 128;

    // ---- CSR build + weight transpose/convert
    k_init<<<cdiv(NN, 256), 256, 0, stream>>>(deg, cursor, stats);
    k_deg<<<cdiv(EE, 256), 256, 0, stream>>>(col, deg);
    k_dinv<<<cdiv(NN, 256), 256, 0, stream>>>(deg, dinv);
    k_scan<<<1, 1024, 0, stream>>>(deg, offs);
    k_scatter<<<cdiv(EE, 256), 256, 0, stream>>>(row, col, dinv, offs, cursor, ep);
    k_wt<<<cdiv(4 * 128 * 512, 256), 256, 0, stream>>>(W1, W1T, 128, 512, 4 * 128 * 512);
    k_wt<<<cdiv(4 * 512 * 512, 256), 256, 0, stream>>>(W2, W2T, 512, 512, 4 * 512 * 512);
    k_wt3<<<cdiv(64 * 512, 256), 256, 0, stream>>>(W3, W3T);

    dim3 gg(512 / 64, cdiv(NN, 128));  // (8, 782), 128x64 tiles
    const size_t WQ = (size_t)512 * 512;   // per-hop stride in W2T
    const size_t W1Q = (size_t)512 * 128;  // per-hop stride in W1T

    // ---- layer 1: h1(H1) = relu(sum_k (A^k x) W1[k] + b1); stats fused in GEMM2
    k_cvt<<<cdiv(NN * 32, 256), 256, 0, stream>>>(x, xb, NN * 32);
    k_prop_t<0><<<NN, 64, 0, stream>>>(xb, 128, F8a, 128, offs, ep);   // hop1 fp8
    k_gemm_mfma<<<gg, 256, 0, stream>>>(xb, 128, F8a, 128, xb, 128, xb, 128, 2, W1T,
                                        W1T + W1Q, W1T, W1T, 128, H1, 512, NN, 256, 128,
                                        nullptr, 0, 1, nullptr);
    k_prop_t<1><<<NN, 64, 0, stream>>>(F8a, 128, F8b, 128, offs, ep);  // hop2 fp8
    k_prop_t<1><<<NN, 64, 0, stream>>>(F8b, 128, F8a, 128, offs, ep);  // hop3 fp8
    k_gemm_mfma<<<gg, 256, 0, stream>>>(F8b, 128, F8a, 128, xb, 128, xb, 128, 3,
                                        W1T + 2 * W1Q, W1T + 3 * W1Q, W1T, W1T, 128, H1, 512,
                                        NN, 256, 128, b1, 1, 2, stats);
    k_gnorm<<<NN, 256, 0, stream>>>(H1, 512, stats, g1w, g1b, g1a);

    // ---- layer 2: Y = sum_k (A^k h1) W2[k], 2 chunks of width 256.
    // Per chunk: GEMM(k=0, bf16 h1 chunk) FIRST -> chunk slice dies -> hosts hop1/hop2 fp8;
    // hop3 lands in X8 (dead after hop1 consumed it). One K=768 GEMM for k=1..3.
    for (int c = 0; c < 2; ++c) {
        u16* h1c = H1 + 256 * c;  // ld 512, bf16, alive until GEMM1 consumed it
        k_cvt8s<<<cdiv(NN * 128, 256), 256, 0, stream>>>(h1c, 512, X8, 256);  // fp8 copy
        k_gemm_mfma<<<gg, 256, 0, stream>>>(h1c, 512, h1c, 512, h1c, 512, h1c, 512, 0,
                                            W2T + 256 * c, W2T, W2T, W2T, 512, Y, 512, NN, 256,
                                            256, nullptr, 0, c == 0 ? 1 : 2, nullptr);
        unsigned char* hp1 = (unsigned char*)H1 + 512 * c;  // dead slice: 512 B/row
        unsigned char* hp2 = hp1 + 256;
        k_prop256<<<NN, 64, 0, stream>>>(X8, 256, hp1, 1024, offs, ep);   // hop1
        k_prop256<<<NN, 64, 0, stream>>>(hp1, 1024, hp2, 1024, offs, ep); // hop2
        k_prop256<<<NN, 64, 0, stream>>>(hp2, 1024, X8, 256, offs, ep);   // hop3 (X8 dead)
        k_gemm_mfma<<<gg, 256, 0, stream>>>(hp1, 1024, hp2, 1024, X8, 256, X8, 256, 7,
                                            W2T + WQ + 256 * c, W2T + 2 * WQ + 256 * c,
                                            W2T + 3 * WQ + 256 * c, W2T, 512, Y, 512, NN, 768,
                                            256, (c == 1) ? b2 : nullptr, c == 1 ? 1 : 0, 2,
                                            (c == 1) ? (stats + 1024) : nullptr);
    }
    k_gnorm<<<NN, 256, 0, stream>>>(Y, 512, stats + 1024, g2w, g2b, g2a);

    // ---- layer 3 (Horner at width 16): G = h2 @ [W3_0|W3_1|W3_2|W3_3] (fp32, H1 dead)
    float* G = (float*)H1;             // N x 64 fp32 = 25.6 MB
    float* tA = (float*)X8;            // N x 16 fp32 = 6.4 MB
    float* tB = tA + (size_t)NN * 16;  // 6.4 MB (X8 = 25.6 MB holds both)
    {
        dim3 g3(1, cdiv(NN, 128));
        k_gemm_mfma<<<g3, 256, 0, stream>>>(Y, 512, Y, 512, Y, 512, Y, 512, 0, W3T, W3T, W3T,
                                            W3T, 512, G, 64, NN, 512, 512, nullptr, 0, 0,
                                            nullptr);
    }
    k_prop16<<<cdiv(NN, 16), 256, 0, stream>>>(G + 48, 64, G + 32, 64, tA, nullptr, offs, ep);
    k_prop16<<<cdiv(NN, 16), 256, 0, stream>>>(tA, 16, G + 16, 64, tB, nullptr, offs, ep);
    k_prop16<<<cdiv(NN, 16), 256, 0, stream>>>(tB, 16, G + 0, 64, (float*)d_out, b3, offs, ep);
}